// Round 1
// baseline (2568.571 us; speedup 1.0000x reference)
//
#include <hip/hip_runtime.h>
#include <math.h>

#define CDIM 384
#define LNEPS 1e-6f

// ---------------- LN stats: one wave per row ----------------
__global__ __launch_bounds__(256) void ln_stats_kernel(
    const float* __restrict__ src, float* __restrict__ mu,
    float* __restrict__ rs, int rows) {
    int row = blockIdx.x * 4 + (threadIdx.x >> 6);
    int lane = threadIdx.x & 63;
    if (row >= rows) return;
    const float* p = src + (size_t)row * CDIM;
    float s = 0.f, sq = 0.f;
#pragma unroll
    for (int i = 0; i < CDIM / 64; ++i) {
        float v = p[lane + 64 * i];
        s += v; sq += v * v;
    }
#pragma unroll
    for (int off = 32; off > 0; off >>= 1) {
        s += __shfl_down(s, off);
        sq += __shfl_down(sq, off);
    }
    if (lane == 0) {
        float m = s / (float)CDIM;
        float var = sq / (float)CDIM - m * m;
        mu[row] = m;
        rs[row] = rsqrtf(var + LNEPS);
    }
}

// ---------------- generic fp32 GEMM: C[b] = act(LN(A[b]) @ B + bias) ----------------
// A rows mapped through (row % rowmod); stats indexed b*rowmod + srow.
// K fixed = 384. Tiles 64x64x16, 256 threads, 4x4 per thread.
__global__ __launch_bounds__(256) void gemm_kernel(
    const float* __restrict__ A, int strideAb, int rowmod,
    const float* __restrict__ B, int N,
    const float* __restrict__ bias,
    float* __restrict__ Cout, int strideCb,
    const float* __restrict__ mu, const float* __restrict__ rs,
    const float* __restrict__ lng, const float* __restrict__ lnb,
    int act) {
    __shared__ float As[16][68];   // transposed A tile [k][m]
    __shared__ float Bs[16][64];
    int b = blockIdx.z;
    int m0 = blockIdx.y * 64;
    int n0 = blockIdx.x * 64;
    int tid = threadIdx.x;
    const float* Ab = A + (size_t)b * strideAb;
    float acc[4][4] = {};
    int ar = tid >> 2;   // A row in tile 0..63
    int ac = tid & 3;    // A float4 col 0..3
    int br = tid >> 4;   // B k-row 0..15
    int bc = tid & 15;   // B float4 col 0..15
    int tm = tid >> 4;   // out row group
    int tn = tid & 15;   // out col group
    int srow = (m0 + ar) % rowmod;
    float rmu = 0.f, rrs = 1.f;
    if (mu) {
        int si = b * rowmod + srow;
        rmu = mu[si]; rrs = rs[si];
    }
    const float* arow_p = Ab + (size_t)srow * CDIM;
    for (int k0 = 0; k0 < CDIM; k0 += 16) {
        float4 av = *(const float4*)(arow_p + k0 + ac * 4);
        float va[4] = {av.x, av.y, av.z, av.w};
        if (mu) {
#pragma unroll
            for (int j = 0; j < 4; ++j) {
                int k = k0 + ac * 4 + j;
                va[j] = (va[j] - rmu) * rrs * lng[k] + lnb[k];
            }
        }
#pragma unroll
        for (int j = 0; j < 4; ++j) As[ac * 4 + j][ar] = va[j];
        *(float4*)(&Bs[br][bc * 4]) =
            *(const float4*)(B + (size_t)(k0 + br) * N + n0 + bc * 4);
        __syncthreads();
#pragma unroll
        for (int k = 0; k < 16; ++k) {
            float4 a4 = *(const float4*)(&As[k][tm * 4]);
            float4 b4 = *(const float4*)(&Bs[k][tn * 4]);
            float aa[4] = {a4.x, a4.y, a4.z, a4.w};
            float bb[4] = {b4.x, b4.y, b4.z, b4.w};
#pragma unroll
            for (int i = 0; i < 4; ++i)
#pragma unroll
                for (int j = 0; j < 4; ++j)
                    acc[i][j] += aa[i] * bb[j];
        }
        __syncthreads();
    }
#pragma unroll
    for (int i = 0; i < 4; ++i) {
        int row = m0 + tm * 4 + i;
        float4 o;
        float* op = (float*)&o;
#pragma unroll
        for (int j = 0; j < 4; ++j) {
            int col = n0 + tn * 4 + j;
            float v = acc[i][j];
            if (bias) v += bias[col];
            if (act == 1) v = tanhf(v);
            op[j] = v;
        }
        *(float4*)(Cout + (size_t)b * strideCb + (size_t)row * N + n0 + tn * 4) = o;
    }
}

// ---------------- flash attention (fp32, online softmax) ----------------
// Q: [b, QN, 384], head h cols h*HD..; KV: [b, N, 768], K cols h*HD, V cols 384+h*HD.
// O: [b, QN, 384] head cols. Optional multiplicative gaussian on logits (main attn).
template <int HD>
__global__ __launch_bounds__(256) void flash_kernel(
    const float* __restrict__ Qb, int strideQb,
    const float* __restrict__ KVb, int strideKVb,
    float* __restrict__ Ob, int strideOb,
    const float* __restrict__ pt,
    int N, float scale, int useGauss) {
    constexpr int HDP = HD + 4;
    constexpr int DS = HD / 8;
    __shared__ float Qs[32][HDP];
    __shared__ float Ks[32][HDP];
    __shared__ float Vs[32][HDP];
    __shared__ float Sv[32][33];
    __shared__ float mrow[32], lrow[32], arow[32];
    int b = blockIdx.z;
    int h = blockIdx.y;
    int q0 = blockIdx.x * 32;
    int tid = threadIdx.x;
    const float* Q = Qb + (size_t)b * strideQb;
    const float* KV = KVb + (size_t)b * strideKVb;
    float* O = Ob + (size_t)b * strideOb;

    for (int i = tid; i < 32 * HD / 4; i += 256) {
        int row = i / (HD / 4);
        int dc = i % (HD / 4);
        float4 v = *(const float4*)(Q + (size_t)(q0 + row) * CDIM + h * HD + dc * 4);
        v.x *= scale; v.y *= scale; v.z *= scale; v.w *= scale;
        *(float4*)(&Qs[row][dc * 4]) = v;
    }
    if (tid < 32) { mrow[tid] = -1e30f; lrow[tid] = 0.f; }
    float acc[DS];
#pragma unroll
    for (int d = 0; d < DS; ++d) acc[d] = 0.f;
    int q = tid >> 3;
    int kb = (tid & 7) * 4;
    int dg = tid & 7;
    __syncthreads();

    for (int n0 = 0; n0 < N; n0 += 32) {
        for (int i = tid; i < 32 * HD / 4; i += 256) {
            int row = i / (HD / 4);
            int dc = i % (HD / 4);
            const float* kp = KV + (size_t)(n0 + row) * 768 + h * HD + dc * 4;
            *(float4*)(&Ks[row][dc * 4]) = *(const float4*)kp;
            *(float4*)(&Vs[row][dc * 4]) = *(const float4*)(kp + CDIM);
        }
        __syncthreads();
        // S = Q K^T  (each thread: 1 q row x 4 k rows)
        float s[4] = {0.f, 0.f, 0.f, 0.f};
        for (int dc = 0; dc < HD / 4; ++dc) {
            float4 qv = *(const float4*)(&Qs[q][dc * 4]);
#pragma unroll
            for (int j = 0; j < 4; ++j) {
                float4 kv4 = *(const float4*)(&Ks[kb + j][dc * 4]);
                s[j] += qv.x * kv4.x + qv.y * kv4.y + qv.z * kv4.z + qv.w * kv4.w;
            }
        }
        if (useGauss) {
#pragma unroll
            for (int j = 0; j < 4; ++j) {
                int kg = n0 + kb + j;
                int w = kg & 127;
                float ptv = pt[(size_t)b * 512 + (size_t)(q0 + q) * 8 + (kg >> 7)];
                float dlt = (float)w - ptv;
                s[j] *= __expf(-dlt * dlt * (1.f / 18.f));
            }
        }
#pragma unroll
        for (int j = 0; j < 4; ++j) Sv[q][kb + j] = s[j];
        __syncthreads();
        if (tid < 32) {
            int qq = tid;
            float mold = mrow[qq];
            float mx = mold;
#pragma unroll
            for (int k = 0; k < 32; ++k) mx = fmaxf(mx, Sv[qq][k]);
            float al = __expf(mold - mx);
            float sum = 0.f;
#pragma unroll
            for (int k = 0; k < 32; ++k) {
                float p = __expf(Sv[qq][k] - mx);
                Sv[qq][k] = p;
                sum += p;
            }
            mrow[qq] = mx;
            lrow[qq] = lrow[qq] * al + sum;
            arow[qq] = al;
        }
        __syncthreads();
        float al = arow[q];
#pragma unroll
        for (int d = 0; d < DS; ++d) acc[d] *= al;
        for (int k = 0; k < 32; ++k) {
            float p = Sv[q][k];
#pragma unroll
            for (int dc = 0; dc < DS / 2; ++dc) {
                float2 v = *(const float2*)(&Vs[k][dg * DS + dc * 2]);
                acc[dc * 2 + 0] += p * v.x;
                acc[dc * 2 + 1] += p * v.y;
            }
        }
        __syncthreads();
    }
    float li = 1.f / lrow[q];
#pragma unroll
    for (int dc = 0; dc < DS / 2; ++dc) {
        float2 o;
        o.x = acc[dc * 2 + 0] * li;
        o.y = acc[dc * 2 + 1] * li;
        *(float2*)(O + (size_t)(q0 + q) * CDIM + h * HD + dg * DS + dc * 2) = o;
    }
}

// ---------------- p_t head: sigmoid(T . vp_w + vp_b) * 128 ----------------
__global__ __launch_bounds__(256) void pt_kernel(
    const float* __restrict__ T, const float* __restrict__ vpw,
    const float* __restrict__ vpb, float* __restrict__ pt, int rows) {
    int row = blockIdx.x * 4 + (threadIdx.x >> 6);
    int lane = threadIdx.x & 63;
    if (row >= rows) return;
    const float* p = T + (size_t)row * CDIM;
    float s = 0.f;
#pragma unroll
    for (int i = 0; i < CDIM / 64; ++i) s += p[lane + 64 * i] * vpw[lane + 64 * i];
#pragma unroll
    for (int off = 32; off > 0; off >>= 1) s += __shfl_down(s, off);
    if (lane == 0) {
        float x = s + vpb[0];
        pt[row] = 128.f / (1.f + __expf(-x));
    }
}

extern "C" void kernel_launch(void* const* d_in, const int* in_sizes, int n_in,
                              void* d_out, int out_size, void* d_ws, size_t ws_size,
                              hipStream_t stream) {
    const float* q       = (const float*)d_in[0];
    const float* kv      = (const float*)d_in[1];
    const float* Wq      = (const float*)d_in[2];
    const float* Wkv     = (const float*)d_in[3];
    const float* Wproj   = (const float*)d_in[4];
    const float* bproj   = (const float*)d_in[5];
    const float* Wp_w    = (const float*)d_in[6];
    const float* Wp_b    = (const float*)d_in[7];
    const float* vp_w    = (const float*)d_in[8];
    const float* vp_b    = (const float*)d_in[9];
    const float* qpos_w  = (const float*)d_in[10];
    const float* qpos_b  = (const float*)d_in[11];
    const float* ca1_Wq  = (const float*)d_in[12];
    const float* ca1_Wkv = (const float*)d_in[13];
    const float* ca1_Wp  = (const float*)d_in[14];
    const float* ca1_bp  = (const float*)d_in[15];
    const float* ca2_Wq  = (const float*)d_in[16];
    const float* ca2_Wkv = (const float*)d_in[17];
    const float* ca2_Wp  = (const float*)d_in[18];
    const float* ca2_bp  = (const float*)d_in[19];
    const float* lnq1_g  = (const float*)d_in[20];
    const float* lnq1_b  = (const float*)d_in[21];
    const float* lnkv1_g = (const float*)d_in[22];
    const float* lnkv1_b = (const float*)d_in[23];
    const float* lnq2_g  = (const float*)d_in[24];
    const float* lnq2_b  = (const float*)d_in[25];
    const float* lnkv2_g = (const float*)d_in[26];
    const float* lnkv2_b = (const float*)d_in[27];
    float* out = (float*)d_out;

    float* ws = (float*)d_ws;
    float* R0 = ws;                  // 6,291,456 f : P_A / CAX / QP+X
    float* R1 = ws + 6291456;        // 6,291,456 f : P_B / P
    float* R2 = ws + 12582912;       // 6,291,456 f : CAQ / T
    float* R3 = ws + 18874368;       // 25,165,824 f: CAKV / KVP
    float* MU = ws + 44040192;       // 32768 f
    float* RS = MU + 32768;          // 32768 f
    float* PT = RS + 32768;          // 16384 f

    const float SC_CA = 0.07216878364870323f;   // 192^-0.5
    const float SC_MA = 0.14433756729740643f;   // 48^-0.5
    dim3 blk(256);

    // 1. P_A(R0) = tile(q,H) @ qpos_w + qpos_b
    gemm_kernel<<<dim3(6, 8, 32), blk, 0, stream>>>(
        q, 24576, 64, qpos_w, 384, qpos_b, R0, 196608,
        nullptr, nullptr, nullptr, nullptr, 0);
    // 2. CA1: CAQ(R2) = LN(P_A) @ ca1_Wq
    ln_stats_kernel<<<4096, blk, 0, stream>>>(R0, MU, RS, 16384);
    gemm_kernel<<<dim3(6, 8, 32), blk, 0, stream>>>(
        R0, 196608, 512, ca1_Wq, 384, nullptr, R2, 196608,
        MU, RS, lnq1_g, lnq1_b, 0);
    //    CAKV(R3) = LN(tile(q,H)) @ ca1_Wkv
    ln_stats_kernel<<<512, blk, 0, stream>>>(q, MU, RS, 2048);
    gemm_kernel<<<dim3(12, 8, 32), blk, 0, stream>>>(
        q, 24576, 64, ca1_Wkv, 768, nullptr, R3, 393216,
        MU, RS, lnkv1_g, lnkv1_b, 0);
    //    flash ca1 -> CAX(R0)
    flash_kernel<192><<<dim3(16, 2, 32), blk, 0, stream>>>(
        R2, 196608, R3, 393216, R0, 196608, nullptr, 512, SC_CA, 0);
    //    P_B(R1) = CAX @ ca1_Wproj + ca1_bproj
    gemm_kernel<<<dim3(6, 8, 32), blk, 0, stream>>>(
        R0, 196608, 512, ca1_Wp, 384, ca1_bp, R1, 196608,
        nullptr, nullptr, nullptr, nullptr, 0);
    // 3. CA2: CAQ(R2) = LN(P_B) @ ca2_Wq
    ln_stats_kernel<<<4096, blk, 0, stream>>>(R1, MU, RS, 16384);
    gemm_kernel<<<dim3(6, 8, 32), blk, 0, stream>>>(
        R1, 196608, 512, ca2_Wq, 384, nullptr, R2, 196608,
        MU, RS, lnq2_g, lnq2_b, 0);
    //    CAKV(R3) = LN(kv) @ ca2_Wkv
    ln_stats_kernel<<<8192, blk, 0, stream>>>(kv, MU, RS, 32768);
    gemm_kernel<<<dim3(12, 16, 32), blk, 0, stream>>>(
        kv, 393216, 1024, ca2_Wkv, 768, nullptr, R3, 786432,
        MU, RS, lnkv2_g, lnkv2_b, 0);
    //    flash ca2 -> CAX(R0)
    flash_kernel<192><<<dim3(16, 2, 32), blk, 0, stream>>>(
        R2, 196608, R3, 786432, R0, 196608, nullptr, 1024, SC_CA, 0);
    //    P(R1) = CAX @ ca2_Wproj + ca2_bproj
    gemm_kernel<<<dim3(6, 8, 32), blk, 0, stream>>>(
        R0, 196608, 512, ca2_Wp, 384, ca2_bp, R1, 196608,
        nullptr, nullptr, nullptr, nullptr, 0);
    // 4. T(R2) = tanh(P @ Wp_w + Wp_b); PT = sigmoid(T.vp_w + vp_b)*128
    gemm_kernel<<<dim3(6, 8, 32), blk, 0, stream>>>(
        R1, 196608, 512, Wp_w, 384, Wp_b, R2, 196608,
        nullptr, nullptr, nullptr, nullptr, 1);
    pt_kernel<<<4096, blk, 0, stream>>>(R2, vp_w, vp_b, PT, 16384);
    // 5. main attention
    gemm_kernel<<<dim3(6, 1, 32), blk, 0, stream>>>(
        q, 24576, 64, Wq, 384, nullptr, R0, 24576,
        nullptr, nullptr, nullptr, nullptr, 0);            // QP(R0)
    gemm_kernel<<<dim3(12, 16, 32), blk, 0, stream>>>(
        kv, 393216, 1024, Wkv, 768, nullptr, R3, 786432,
        nullptr, nullptr, nullptr, nullptr, 0);            // KVP(R3)
    flash_kernel<48><<<dim3(2, 8, 32), blk, 0, stream>>>(
        R0, 24576, R3, 786432, R0 + 786432, 24576, PT, 1024, SC_MA, 1);
    // 6. out = X @ Wproj + bproj
    gemm_kernel<<<dim3(6, 1, 32), blk, 0, stream>>>(
        R0 + 786432, 24576, 64, Wproj, 384, bproj, out, 24576,
        nullptr, nullptr, nullptr, nullptr, 0);
}

// Round 2
// 1899.902 us; speedup vs baseline: 1.3519x; 1.3519x over previous
//
#include <hip/hip_runtime.h>
#include <math.h>

#define CDIM 384
#define LNEPS 1e-6f

typedef __attribute__((ext_vector_type(8))) short bf16x8;
typedef __attribute__((ext_vector_type(4))) float f32x4;
typedef __attribute__((ext_vector_type(4))) unsigned short us4;
typedef unsigned short ushort_t;

__device__ __forceinline__ unsigned short f2bf(float x) {
    unsigned u = __float_as_uint(x);
    unsigned r = (u + 0x7FFFu + ((u >> 16) & 1u)) >> 16;
    return (unsigned short)r;
}

// ---------------- LN stats: one wave per row ----------------
__global__ __launch_bounds__(256) void ln_stats_kernel(
    const float* __restrict__ src, float* __restrict__ mu,
    float* __restrict__ rs, int rows) {
    int row = blockIdx.x * 4 + (threadIdx.x >> 6);
    int lane = threadIdx.x & 63;
    if (row >= rows) return;
    const float* p = src + (size_t)row * CDIM;
    float s = 0.f, sq = 0.f;
#pragma unroll
    for (int i = 0; i < CDIM / 64; ++i) {
        float v = p[lane + 64 * i];
        s += v; sq += v * v;
    }
#pragma unroll
    for (int off = 32; off > 0; off >>= 1) {
        s += __shfl_down(s, off);
        sq += __shfl_down(sq, off);
    }
    if (lane == 0) {
        float m = s / (float)CDIM;
        float var = sq / (float)CDIM - m * m;
        mu[row] = m;
        rs[row] = rsqrtf(var + LNEPS);
    }
}

// ---------------- weight prep: W[384][N] fp32 -> Wt_h[N][384], Wt_l[N][384] bf16 ----------------
__global__ __launch_bounds__(256) void wprep_kernel(
    const float* __restrict__ W, ushort_t* __restrict__ oh,
    ushort_t* __restrict__ ol, int N) {
    int i = blockIdx.x * 256 + threadIdx.x;   // over N*384
    int n = i / 384, k = i % 384;
    float x = W[(size_t)k * N + n];
    unsigned short h = f2bf(x);
    float hf = __uint_as_float((unsigned)h << 16);
    oh[i] = h;
    ol[i] = f2bf(x - hf);
}

// ---------------- activation split (+optional LN, +row tiling) ----------------
// dst row r: b = r/dpb, sr = b*spb + (r%dpb)%spb ; stats indexed by sr.
__global__ __launch_bounds__(256) void split_ln_kernel(
    const float* __restrict__ src, int spb, int dpb,
    const float* __restrict__ mu, const float* __restrict__ rs,
    const float* __restrict__ g, const float* __restrict__ bt,
    ushort_t* __restrict__ dh, ushort_t* __restrict__ dl) {
    int idx = blockIdx.x * 256 + threadIdx.x;   // float4 index
    int r = idx / 96, c4 = idx % 96;
    int b = r / dpb, rb = r % dpb;
    int sr = b * spb + (rb % spb);
    float4 v = *(const float4*)(src + (size_t)sr * 384 + c4 * 4);
    float vv[4] = {v.x, v.y, v.z, v.w};
    if (mu) {
        float m = mu[sr], s = rs[sr];
#pragma unroll
        for (int jj = 0; jj < 4; ++jj) {
            int c = c4 * 4 + jj;
            vv[jj] = (vv[jj] - m) * s * g[c] + bt[c];
        }
    }
    us4 oh, ol;
#pragma unroll
    for (int jj = 0; jj < 4; ++jj) {
        unsigned short h = f2bf(vv[jj]);
        float hf = __uint_as_float((unsigned)h << 16);
        oh[jj] = h;
        ol[jj] = f2bf(vv[jj] - hf);
    }
    *(us4*)(dh + (size_t)r * 384 + c4 * 4) = oh;
    *(us4*)(dl + (size_t)r * 384 + c4 * 4) = ol;
}

// ---------------- split-bf16 MFMA GEMM ----------------
// C[M][N] = act(A[M][384] @ W[384][N] + bias), A = Ah+Al, W = Wh+Wl (Wt stored [N][384]).
// 3-term: AhWh + AhWl + AlWh. Tile 128x64, BK=64, 4 waves (each 32m x 64n).
__global__ __launch_bounds__(256) void gemm_mfma_kernel(
    const ushort_t* __restrict__ Ah, const ushort_t* __restrict__ Al,
    const ushort_t* __restrict__ Bh, const ushort_t* __restrict__ Bl,
    const float* __restrict__ bias, float* __restrict__ C,
    int N, int act) {
    __shared__ __align__(16) ushort_t Alds[2][128 * 64];
    __shared__ __align__(16) ushort_t Blds[2][64 * 64];
    int m0 = blockIdx.y * 128, n0 = blockIdx.x * 64;
    int tid = threadIdx.x;
    int w = tid >> 6, lane = tid & 63;
    int j = lane & 15, kg = lane >> 4;
    int srow = tid >> 3;      // 0..31
    int sk16 = tid & 7;       // 16B chunk within 64-k tile
    f32x4 acc[2][4];
#pragma unroll
    for (int mi = 0; mi < 2; ++mi)
#pragma unroll
        for (int ni = 0; ni < 4; ++ni)
#pragma unroll
            for (int r = 0; r < 4; ++r) acc[mi][ni][r] = 0.f;

    for (int ks = 0; ks < 6; ++ks) {
        int kbase = ks * 64 + sk16 * 8;
        __syncthreads();
#pragma unroll
        for (int rnd = 0; rnd < 4; ++rnd) {
            int row = srow + rnd * 32;
            size_t ga = (size_t)(m0 + row) * 384 + kbase;
            int off = (row << 6) + ((sk16 ^ (row & 7)) << 3);
            bf16x8 vh = *(const bf16x8*)(Ah + ga);
            bf16x8 vl = *(const bf16x8*)(Al + ga);
            *(bf16x8*)&Alds[0][off] = vh;
            *(bf16x8*)&Alds[1][off] = vl;
            if (rnd < 2) {
                size_t gb = (size_t)(n0 + row) * 384 + kbase;
                bf16x8 wh = *(const bf16x8*)(Bh + gb);
                bf16x8 wl = *(const bf16x8*)(Bl + gb);
                *(bf16x8*)&Blds[0][off] = wh;
                *(bf16x8*)&Blds[1][off] = wl;
            }
        }
        __syncthreads();
#pragma unroll
        for (int kf = 0; kf < 2; ++kf) {
            bf16x8 afh[2], afl[2], bfh[4], bfl[4];
#pragma unroll
            for (int mi = 0; mi < 2; ++mi) {
                int row = w * 32 + mi * 16 + j;
                int off = (row << 6) + (((((kf << 2) | kg)) ^ (row & 7)) << 3);
                afh[mi] = *(const bf16x8*)&Alds[0][off];
                afl[mi] = *(const bf16x8*)&Alds[1][off];
            }
#pragma unroll
            for (int ni = 0; ni < 4; ++ni) {
                int col = ni * 16 + j;
                int off = (col << 6) + (((((kf << 2) | kg)) ^ (col & 7)) << 3);
                bfh[ni] = *(const bf16x8*)&Blds[0][off];
                bfl[ni] = *(const bf16x8*)&Blds[1][off];
            }
#pragma unroll
            for (int mi = 0; mi < 2; ++mi)
#pragma unroll
                for (int ni = 0; ni < 4; ++ni) {
                    acc[mi][ni] = __builtin_amdgcn_mfma_f32_16x16x32_bf16(
                        afh[mi], bfh[ni], acc[mi][ni], 0, 0, 0);
                    acc[mi][ni] = __builtin_amdgcn_mfma_f32_16x16x32_bf16(
                        afh[mi], bfl[ni], acc[mi][ni], 0, 0, 0);
                    acc[mi][ni] = __builtin_amdgcn_mfma_f32_16x16x32_bf16(
                        afl[mi], bfh[ni], acc[mi][ni], 0, 0, 0);
                }
        }
    }
#pragma unroll
    for (int mi = 0; mi < 2; ++mi)
#pragma unroll
        for (int ni = 0; ni < 4; ++ni)
#pragma unroll
            for (int r = 0; r < 4; ++r) {
                int row = m0 + w * 32 + mi * 16 + kg * 4 + r;
                int col = n0 + ni * 16 + j;
                float v = acc[mi][ni][r];
                if (bias) v += bias[col];
                if (act == 1) v = tanhf(v);
                C[(size_t)row * N + col] = v;
            }
}

// ---------------- flash attention (fp32, online softmax, wave-parallel) ----------------
template <int HD>
__global__ __launch_bounds__(256) void flash_kernel(
    const float* __restrict__ Qb, int strideQb,
    const float* __restrict__ KVb, int strideKVb,
    float* __restrict__ Ob, int strideOb,
    const float* __restrict__ pt,
    int N, float scale, int useGauss) {
    constexpr int HDP = HD + 4;
    constexpr int DS = HD / 8;
    __shared__ float Qs[32][HDP];
    __shared__ float Ks[32][HDP];
    __shared__ float Vs[32][HDP];
    __shared__ float Sv[32][33];
    int b = blockIdx.z;
    int h = blockIdx.y;
    int q0 = blockIdx.x * 32;
    int tid = threadIdx.x;
    const float* Q = Qb + (size_t)b * strideQb;
    const float* KV = KVb + (size_t)b * strideKVb;
    float* O = Ob + (size_t)b * strideOb;

    for (int i = tid; i < 32 * HD / 4; i += 256) {
        int row = i / (HD / 4);
        int dc = i % (HD / 4);
        float4 v = *(const float4*)(Q + (size_t)(q0 + row) * CDIM + h * HD + dc * 4);
        v.x *= scale; v.y *= scale; v.z *= scale; v.w *= scale;
        *(float4*)(&Qs[row][dc * 4]) = v;
    }
    float acc[DS];
#pragma unroll
    for (int d = 0; d < DS; ++d) acc[d] = 0.f;
    int q = tid >> 3;
    int kb = (tid & 7) * 4;
    int dg = tid & 7;
    float m_run = -1e30f, l_run = 0.f;
    __syncthreads();

    for (int n0 = 0; n0 < N; n0 += 32) {
        for (int i = tid; i < 32 * HD / 4; i += 256) {
            int row = i / (HD / 4);
            int dc = i % (HD / 4);
            const float* kp = KV + (size_t)(n0 + row) * 768 + h * HD + dc * 4;
            *(float4*)(&Ks[row][dc * 4]) = *(const float4*)kp;
            *(float4*)(&Vs[row][dc * 4]) = *(const float4*)(kp + CDIM);
        }
        __syncthreads();
        float s[4] = {0.f, 0.f, 0.f, 0.f};
        for (int dc = 0; dc < HD / 4; ++dc) {
            float4 qv = *(const float4*)(&Qs[q][dc * 4]);
#pragma unroll
            for (int jj = 0; jj < 4; ++jj) {
                float4 kv4 = *(const float4*)(&Ks[kb + jj][dc * 4]);
                s[jj] += qv.x * kv4.x + qv.y * kv4.y + qv.z * kv4.z + qv.w * kv4.w;
            }
        }
        if (useGauss) {
#pragma unroll
            for (int jj = 0; jj < 4; ++jj) {
                int kg2 = n0 + kb + jj;
                int ww = kg2 & 127;
                float ptv = pt[(size_t)b * 512 + (size_t)(q0 + q) * 8 + (kg2 >> 7)];
                float dlt = (float)ww - ptv;
                s[jj] *= __expf(-dlt * dlt * (1.f / 18.f));
            }
        }
        // wave-parallel online softmax over the 8-lane group sharing q
        float mx = fmaxf(fmaxf(s[0], s[1]), fmaxf(s[2], s[3]));
        mx = fmaxf(mx, __shfl_xor(mx, 1));
        mx = fmaxf(mx, __shfl_xor(mx, 2));
        mx = fmaxf(mx, __shfl_xor(mx, 4));
        float mnew = fmaxf(m_run, mx);
        float p[4], ps = 0.f;
#pragma unroll
        for (int jj = 0; jj < 4; ++jj) {
            p[jj] = __expf(s[jj] - mnew);
            ps += p[jj];
        }
        ps += __shfl_xor(ps, 1);
        ps += __shfl_xor(ps, 2);
        ps += __shfl_xor(ps, 4);
        float al = __expf(m_run - mnew);
        m_run = mnew;
        l_run = l_run * al + ps;
#pragma unroll
        for (int jj = 0; jj < 4; ++jj) Sv[q][kb + jj] = p[jj];
        __syncthreads();
#pragma unroll
        for (int d = 0; d < DS; ++d) acc[d] *= al;
        for (int k = 0; k < 32; ++k) {
            float pv = Sv[q][k];
#pragma unroll
            for (int dc = 0; dc < DS / 2; ++dc) {
                float2 v = *(const float2*)(&Vs[k][dg * DS + dc * 2]);
                acc[dc * 2 + 0] += pv * v.x;
                acc[dc * 2 + 1] += pv * v.y;
            }
        }
        __syncthreads();
    }
    float li = 1.f / l_run;
#pragma unroll
    for (int dc = 0; dc < DS / 2; ++dc) {
        float2 o;
        o.x = acc[dc * 2 + 0] * li;
        o.y = acc[dc * 2 + 1] * li;
        *(float2*)(O + (size_t)(q0 + q) * CDIM + h * HD + dg * DS + dc * 2) = o;
    }
}

// ---------------- p_t head ----------------
__global__ __launch_bounds__(256) void pt_kernel(
    const float* __restrict__ T, const float* __restrict__ vpw,
    const float* __restrict__ vpb, float* __restrict__ pt, int rows) {
    int row = blockIdx.x * 4 + (threadIdx.x >> 6);
    int lane = threadIdx.x & 63;
    if (row >= rows) return;
    const float* p = T + (size_t)row * CDIM;
    float s = 0.f;
#pragma unroll
    for (int i = 0; i < CDIM / 64; ++i) s += p[lane + 64 * i] * vpw[lane + 64 * i];
#pragma unroll
    for (int off = 32; off > 0; off >>= 1) s += __shfl_down(s, off);
    if (lane == 0) {
        float x = s + vpb[0];
        pt[row] = 128.f / (1.f + __expf(-x));
    }
}

extern "C" void kernel_launch(void* const* d_in, const int* in_sizes, int n_in,
                              void* d_out, int out_size, void* d_ws, size_t ws_size,
                              hipStream_t stream) {
    const float* q       = (const float*)d_in[0];
    const float* kv      = (const float*)d_in[1];
    const float* Wq      = (const float*)d_in[2];
    const float* Wkv     = (const float*)d_in[3];
    const float* Wproj   = (const float*)d_in[4];
    const float* bproj   = (const float*)d_in[5];
    const float* Wp_w    = (const float*)d_in[6];
    const float* Wp_b    = (const float*)d_in[7];
    const float* vp_w    = (const float*)d_in[8];
    const float* vp_b    = (const float*)d_in[9];
    const float* qpos_w  = (const float*)d_in[10];
    const float* qpos_b  = (const float*)d_in[11];
    const float* ca1_Wq  = (const float*)d_in[12];
    const float* ca1_Wkv = (const float*)d_in[13];
    const float* ca1_Wp  = (const float*)d_in[14];
    const float* ca1_bp  = (const float*)d_in[15];
    const float* ca2_Wq  = (const float*)d_in[16];
    const float* ca2_Wkv = (const float*)d_in[17];
    const float* ca2_Wp  = (const float*)d_in[18];
    const float* ca2_bp  = (const float*)d_in[19];
    const float* lnq1_g  = (const float*)d_in[20];
    const float* lnq1_b  = (const float*)d_in[21];
    const float* lnkv1_g = (const float*)d_in[22];
    const float* lnkv1_b = (const float*)d_in[23];
    const float* lnq2_g  = (const float*)d_in[24];
    const float* lnq2_b  = (const float*)d_in[25];
    const float* lnkv2_g = (const float*)d_in[26];
    const float* lnkv2_b = (const float*)d_in[27];
    float* out = (float*)d_out;

    float* ws = (float*)d_ws;
    float* R0 = ws;                  // P_A / CAX / QP+X
    float* R1 = ws + 6291456;        // P_B / P
    float* R2 = ws + 12582912;       // CAQ / T
    float* R3 = ws + 18874368;       // CAKV / KVP (25165824 f)
    float* MU = ws + 44040192;
    float* RS = ws + 44072960;
    float* PT = ws + 44105728;
    ushort_t* UB  = (ushort_t*)(ws + 44122112);
    ushort_t* SBh = UB;                       // 12582912 us
    ushort_t* SBl = UB + 12582912;
    ushort_t* WB  = UB + 25165824;
    const int SQ = 147456, KVW = 294912;
    ushort_t* w_qpos = WB;
    ushort_t* w_c1q  = WB + 294912;
    ushort_t* w_c1kv = WB + 589824;
    ushort_t* w_c1p  = WB + 1179648;
    ushort_t* w_c2q  = WB + 1474560;
    ushort_t* w_c2kv = WB + 1769472;
    ushort_t* w_c2p  = WB + 2359296;
    ushort_t* w_wp   = WB + 2654208;
    ushort_t* w_wq   = WB + 2949120;
    ushort_t* w_wkv  = WB + 3244032;
    ushort_t* w_wpr  = WB + 3833856;

    const float SC_CA = 0.07216878364870323f;   // 192^-0.5
    const float SC_MA = 0.14433756729740643f;   // 48^-0.5
    dim3 blk(256);

    // ---- weight prep (transpose + hi/lo split) ----
    wprep_kernel<<<576, blk, 0, stream>>>(qpos_w, w_qpos, w_qpos + SQ, 384);
    wprep_kernel<<<576, blk, 0, stream>>>(ca1_Wq, w_c1q, w_c1q + SQ, 384);
    wprep_kernel<<<1152, blk, 0, stream>>>(ca1_Wkv, w_c1kv, w_c1kv + KVW, 768);
    wprep_kernel<<<576, blk, 0, stream>>>(ca1_Wp, w_c1p, w_c1p + SQ, 384);
    wprep_kernel<<<576, blk, 0, stream>>>(ca2_Wq, w_c2q, w_c2q + SQ, 384);
    wprep_kernel<<<1152, blk, 0, stream>>>(ca2_Wkv, w_c2kv, w_c2kv + KVW, 768);
    wprep_kernel<<<576, blk, 0, stream>>>(ca2_Wp, w_c2p, w_c2p + SQ, 384);
    wprep_kernel<<<576, blk, 0, stream>>>(Wp_w, w_wp, w_wp + SQ, 384);
    wprep_kernel<<<576, blk, 0, stream>>>(Wq, w_wq, w_wq + SQ, 384);
    wprep_kernel<<<1152, blk, 0, stream>>>(Wkv, w_wkv, w_wkv + KVW, 768);
    wprep_kernel<<<576, blk, 0, stream>>>(Wproj, w_wpr, w_wpr + SQ, 384);

    // ---- 1. P_A = tile(q,H) @ qpos_w + qpos_b ----
    split_ln_kernel<<<6144, blk, 0, stream>>>(q, 64, 512, nullptr, nullptr, nullptr, nullptr, SBh, SBl);
    gemm_mfma_kernel<<<dim3(6, 128), blk, 0, stream>>>(SBh, SBl, w_qpos, w_qpos + SQ, qpos_b, R0, 384, 0);
    // ---- 2. CA1 ----
    ln_stats_kernel<<<4096, blk, 0, stream>>>(R0, MU, RS, 16384);
    split_ln_kernel<<<6144, blk, 0, stream>>>(R0, 512, 512, MU, RS, lnq1_g, lnq1_b, SBh, SBl);
    gemm_mfma_kernel<<<dim3(6, 128), blk, 0, stream>>>(SBh, SBl, w_c1q, w_c1q + SQ, nullptr, R2, 384, 0);
    ln_stats_kernel<<<512, blk, 0, stream>>>(q, MU, RS, 2048);
    split_ln_kernel<<<6144, blk, 0, stream>>>(q, 64, 512, MU, RS, lnkv1_g, lnkv1_b, SBh, SBl);
    gemm_mfma_kernel<<<dim3(12, 128), blk, 0, stream>>>(SBh, SBl, w_c1kv, w_c1kv + KVW, nullptr, R3, 768, 0);
    flash_kernel<192><<<dim3(16, 2, 32), blk, 0, stream>>>(
        R2, 196608, R3, 393216, R0, 196608, nullptr, 512, SC_CA, 0);
    split_ln_kernel<<<6144, blk, 0, stream>>>(R0, 512, 512, nullptr, nullptr, nullptr, nullptr, SBh, SBl);
    gemm_mfma_kernel<<<dim3(6, 128), blk, 0, stream>>>(SBh, SBl, w_c1p, w_c1p + SQ, ca1_bp, R1, 384, 0);
    // ---- 3. CA2 ----
    ln_stats_kernel<<<4096, blk, 0, stream>>>(R1, MU, RS, 16384);
    split_ln_kernel<<<6144, blk, 0, stream>>>(R1, 512, 512, MU, RS, lnq2_g, lnq2_b, SBh, SBl);
    gemm_mfma_kernel<<<dim3(6, 128), blk, 0, stream>>>(SBh, SBl, w_c2q, w_c2q + SQ, nullptr, R2, 384, 0);
    ln_stats_kernel<<<8192, blk, 0, stream>>>(kv, MU, RS, 32768);
    split_ln_kernel<<<12288, blk, 0, stream>>>(kv, 1024, 1024, MU, RS, lnkv2_g, lnkv2_b, SBh, SBl);
    gemm_mfma_kernel<<<dim3(12, 256), blk, 0, stream>>>(SBh, SBl, w_c2kv, w_c2kv + KVW, nullptr, R3, 768, 0);
    flash_kernel<192><<<dim3(16, 2, 32), blk, 0, stream>>>(
        R2, 196608, R3, 786432, R0, 196608, nullptr, 1024, SC_CA, 0);
    split_ln_kernel<<<6144, blk, 0, stream>>>(R0, 512, 512, nullptr, nullptr, nullptr, nullptr, SBh, SBl);
    gemm_mfma_kernel<<<dim3(6, 128), blk, 0, stream>>>(SBh, SBl, w_c2p, w_c2p + SQ, ca2_bp, R1, 384, 0);
    // ---- 4. T = tanh(P @ Wp_w + Wp_b); PT ----
    split_ln_kernel<<<6144, blk, 0, stream>>>(R1, 512, 512, nullptr, nullptr, nullptr, nullptr, SBh, SBl);
    gemm_mfma_kernel<<<dim3(6, 128), blk, 0, stream>>>(SBh, SBl, w_wp, w_wp + SQ, Wp_b, R2, 384, 1);
    pt_kernel<<<4096, blk, 0, stream>>>(R2, vp_w, vp_b, PT, 16384);
    // ---- 5. main attention ----
    split_ln_kernel<<<768, blk, 0, stream>>>(q, 64, 64, nullptr, nullptr, nullptr, nullptr, SBh, SBl);
    gemm_mfma_kernel<<<dim3(6, 16), blk, 0, stream>>>(SBh, SBl, w_wq, w_wq + SQ, nullptr, R0, 384, 0);
    split_ln_kernel<<<12288, blk, 0, stream>>>(kv, 1024, 1024, nullptr, nullptr, nullptr, nullptr, SBh, SBl);
    gemm_mfma_kernel<<<dim3(12, 256), blk, 0, stream>>>(SBh, SBl, w_wkv, w_wkv + KVW, nullptr, R3, 768, 0);
    flash_kernel<48><<<dim3(2, 8, 32), blk, 0, stream>>>(
        R0, 24576, R3, 786432, R0 + 786432, 24576, PT, 1024, SC_MA, 1);
    // ---- 6. out ----
    split_ln_kernel<<<768, blk, 0, stream>>>(R0 + 786432, 64, 64, nullptr, nullptr, nullptr, nullptr, SBh, SBl);
    gemm_mfma_kernel<<<dim3(6, 16), blk, 0, stream>>>(SBh, SBl, w_wpr, w_wpr + SQ, bproj, out, 384, 0);
}

// Round 3
// 1027.118 us; speedup vs baseline: 2.5008x; 1.8497x over previous
//
#include <hip/hip_runtime.h>
#include <math.h>

#define CDIM 384
#define LNEPS 1e-6f
#define MFMA __builtin_amdgcn_mfma_f32_16x16x32_bf16

typedef __attribute__((ext_vector_type(8))) short bf16x8;
typedef __attribute__((ext_vector_type(4))) float f32x4;
typedef __attribute__((ext_vector_type(4))) unsigned short us4;
typedef unsigned short ushort_t;

__device__ __forceinline__ unsigned short f2bf(float x) {
    unsigned u = __float_as_uint(x);
    unsigned r = (u + 0x7FFFu + ((u >> 16) & 1u)) >> 16;
    return (unsigned short)r;
}
__device__ __forceinline__ float bfhi(unsigned short h) {
    return __uint_as_float((unsigned)h << 16);
}

// ---------------- LN stats ----------------
__global__ __launch_bounds__(256) void ln_stats_kernel(
    const float* __restrict__ src, float* __restrict__ mu,
    float* __restrict__ rs, int rows) {
    int row = blockIdx.x * 4 + (threadIdx.x >> 6);
    int lane = threadIdx.x & 63;
    if (row >= rows) return;
    const float* p = src + (size_t)row * CDIM;
    float s = 0.f, sq = 0.f;
#pragma unroll
    for (int i = 0; i < CDIM / 64; ++i) {
        float v = p[lane + 64 * i];
        s += v; sq += v * v;
    }
#pragma unroll
    for (int off = 32; off > 0; off >>= 1) {
        s += __shfl_down(s, off);
        sq += __shfl_down(sq, off);
    }
    if (lane == 0) {
        float m = s / (float)CDIM;
        float var = sq / (float)CDIM - m * m;
        mu[row] = m;
        rs[row] = rsqrtf(var + LNEPS);
    }
}

// ---------------- weight prep ----------------
__global__ __launch_bounds__(256) void wprep_kernel(
    const float* __restrict__ W, ushort_t* __restrict__ oh,
    ushort_t* __restrict__ ol, int N) {
    int i = blockIdx.x * 256 + threadIdx.x;
    int n = i / 384, k = i % 384;
    float x = W[(size_t)k * N + n];
    unsigned short h = f2bf(x);
    oh[i] = h;
    ol[i] = f2bf(x - bfhi(h));
}

// ---------------- activation split (+optional LN, +row tiling) ----------------
__global__ __launch_bounds__(256) void split_ln_kernel(
    const float* __restrict__ src, int spb, int dpb,
    const float* __restrict__ mu, const float* __restrict__ rs,
    const float* __restrict__ g, const float* __restrict__ bt,
    ushort_t* __restrict__ dh, ushort_t* __restrict__ dl) {
    int idx = blockIdx.x * 256 + threadIdx.x;
    int r = idx / 96, c4 = idx % 96;
    int b = r / dpb, rb = r % dpb;
    int sr = b * spb + (rb % spb);
    float4 v = *(const float4*)(src + (size_t)sr * 384 + c4 * 4);
    float vv[4] = {v.x, v.y, v.z, v.w};
    if (mu) {
        float m = mu[sr], s = rs[sr];
#pragma unroll
        for (int jj = 0; jj < 4; ++jj) {
            int c = c4 * 4 + jj;
            vv[jj] = (vv[jj] - m) * s * g[c] + bt[c];
        }
    }
    us4 oh, ol;
#pragma unroll
    for (int jj = 0; jj < 4; ++jj) {
        unsigned short h = f2bf(vv[jj]);
        oh[jj] = h;
        ol[jj] = f2bf(vv[jj] - bfhi(h));
    }
    *(us4*)(dh + (size_t)r * 384 + c4 * 4) = oh;
    *(us4*)(dl + (size_t)r * 384 + c4 * 4) = ol;
}

// ---------------- split-bf16 MFMA GEMM with epilogue modes ----------------
// mode 0: Cf = v+bias (fp32) ; mode 3: Cf = tanh(v+bias)
// mode 1: split((v+bias)*scale) -> Ch/Cl [row][N]
// mode 2: col<384 -> Ch/Cl[row][384] (K); col>=384 -> Voh/Vol[b*384+col-384][key] (V^T), Nkv=1<<nkv_sh
__global__ __launch_bounds__(256) void gemm_mfma_kernel(
    const ushort_t* __restrict__ Ah, const ushort_t* __restrict__ Al,
    const ushort_t* __restrict__ Bh, const ushort_t* __restrict__ Bl,
    const float* __restrict__ bias, int N, int mode, float scale, int nkv_sh,
    float* __restrict__ Cf, ushort_t* __restrict__ Ch, ushort_t* __restrict__ Cl,
    ushort_t* __restrict__ Voh, ushort_t* __restrict__ Vol) {
    __shared__ __align__(16) ushort_t Alds[2][128 * 64];
    __shared__ __align__(16) ushort_t Blds[2][64 * 64];
    int m0 = blockIdx.y * 128, n0 = blockIdx.x * 64;
    int tid = threadIdx.x;
    int w = tid >> 6, lane = tid & 63;
    int j = lane & 15, kg = lane >> 4;
    int srow = tid >> 3;
    int sk16 = tid & 7;
    f32x4 acc[2][4];
#pragma unroll
    for (int mi = 0; mi < 2; ++mi)
#pragma unroll
        for (int ni = 0; ni < 4; ++ni)
#pragma unroll
            for (int r = 0; r < 4; ++r) acc[mi][ni][r] = 0.f;

    for (int ks = 0; ks < 6; ++ks) {
        int kbase = ks * 64 + sk16 * 8;
        __syncthreads();
#pragma unroll
        for (int rnd = 0; rnd < 4; ++rnd) {
            int row = srow + rnd * 32;
            size_t ga = (size_t)(m0 + row) * 384 + kbase;
            int off = (row << 6) + ((sk16 ^ (row & 7)) << 3);
            *(bf16x8*)&Alds[0][off] = *(const bf16x8*)(Ah + ga);
            *(bf16x8*)&Alds[1][off] = *(const bf16x8*)(Al + ga);
            if (rnd < 2) {
                size_t gb = (size_t)(n0 + row) * 384 + kbase;
                *(bf16x8*)&Blds[0][off] = *(const bf16x8*)(Bh + gb);
                *(bf16x8*)&Blds[1][off] = *(const bf16x8*)(Bl + gb);
            }
        }
        __syncthreads();
#pragma unroll
        for (int kf = 0; kf < 2; ++kf) {
            bf16x8 afh[2], afl[2], bfh[4], bfl[4];
#pragma unroll
            for (int mi = 0; mi < 2; ++mi) {
                int row = w * 32 + mi * 16 + j;
                int off = (row << 6) + ((((kf << 2) | kg) ^ (row & 7)) << 3);
                afh[mi] = *(const bf16x8*)&Alds[0][off];
                afl[mi] = *(const bf16x8*)&Alds[1][off];
            }
#pragma unroll
            for (int ni = 0; ni < 4; ++ni) {
                int col = ni * 16 + j;
                int off = (col << 6) + ((((kf << 2) | kg) ^ (col & 7)) << 3);
                bfh[ni] = *(const bf16x8*)&Blds[0][off];
                bfl[ni] = *(const bf16x8*)&Blds[1][off];
            }
#pragma unroll
            for (int mi = 0; mi < 2; ++mi)
#pragma unroll
                for (int ni = 0; ni < 4; ++ni) {
                    acc[mi][ni] = MFMA(afh[mi], bfh[ni], acc[mi][ni], 0, 0, 0);
                    acc[mi][ni] = MFMA(afh[mi], bfl[ni], acc[mi][ni], 0, 0, 0);
                    acc[mi][ni] = MFMA(afl[mi], bfh[ni], acc[mi][ni], 0, 0, 0);
                }
        }
    }
#pragma unroll
    for (int mi = 0; mi < 2; ++mi)
#pragma unroll
        for (int ni = 0; ni < 4; ++ni)
#pragma unroll
            for (int r = 0; r < 4; ++r) {
                int row = m0 + w * 32 + mi * 16 + kg * 4 + r;
                int col = n0 + ni * 16 + j;
                float v = acc[mi][ni][r];
                if (bias) v += bias[col];
                if (mode == 0) {
                    Cf[(size_t)row * N + col] = v;
                } else if (mode == 3) {
                    Cf[(size_t)row * N + col] = tanhf(v);
                } else if (mode == 1) {
                    v *= scale;
                    unsigned short hh = f2bf(v);
                    Ch[(size_t)row * N + col] = hh;
                    Cl[(size_t)row * N + col] = f2bf(v - bfhi(hh));
                } else {
                    if (col < 384) {
                        unsigned short hh = f2bf(v);
                        Ch[(size_t)row * 384 + col] = hh;
                        Cl[(size_t)row * 384 + col] = f2bf(v - bfhi(hh));
                    } else {
                        int bb = row >> nkv_sh;
                        int key = row & ((1 << nkv_sh) - 1);
                        size_t o = ((size_t)(bb * 384 + col - 384) << nkv_sh) + key;
                        unsigned short hh = f2bf(v);
                        Voh[o] = hh;
                        Vol[o] = f2bf(v - bfhi(hh));
                    }
                }
            }
}

// ---------------- MFMA flash attention (split-bf16, online softmax) ----------------
// Q pre-scaled split [b][QR][384] head cols h*HD; K split [b][N][384]; Vt split [b][384][N].
// X out split [b][QR][384]. GAUSS: multiplicative exp(-(w-pt)^2/18) on logits.
template <int HD, int DPAD, int NW, int GAUSS>
__global__ __launch_bounds__(64 * NW) void attn_mfma_kernel(
    const ushort_t* __restrict__ Qh, const ushort_t* __restrict__ Ql, int QR,
    const ushort_t* __restrict__ Kh, const ushort_t* __restrict__ Kl,
    const ushort_t* __restrict__ Vth, const ushort_t* __restrict__ Vtl,
    const float* __restrict__ PT,
    ushort_t* __restrict__ Xh, ushort_t* __restrict__ Xl, int N) {
    constexpr int KS = DPAD / 32;
    constexpr int NSUB = HD / 16;
    constexpr int C8 = DPAD / 8;
    constexpr int QT = 16 * NW;
    constexpr int NT = 64 * NW;
    __shared__ __align__(16) ushort_t Ksh[2][32][DPAD + 8];
    __shared__ __align__(16) ushort_t Vsh[2][HD][40];
    __shared__ __align__(16) ushort_t Psh[NW][2][16][40];
    __shared__ float ptbl[GAUSS ? QT : 1][8];
    int b = blockIdx.z, h = blockIdx.y;
    int qbase = blockIdx.x * QT;
    int tid = threadIdx.x;
    int w = tid >> 6, lane = tid & 63;
    int l15 = lane & 15, kg = lane >> 4;

    bf16x8 qf[2][KS];
    {
        size_t qa = (size_t)(b * QR + qbase + w * 16 + l15) * 384 + h * HD + kg * 8;
#pragma unroll
        for (int ks = 0; ks < KS; ++ks) {
            if (ks * 32 + kg * 8 < HD) {
                qf[0][ks] = *(const bf16x8*)(Qh + qa + ks * 32);
                qf[1][ks] = *(const bf16x8*)(Ql + qa + ks * 32);
            } else {
                qf[0][ks] = bf16x8{};
                qf[1][ks] = bf16x8{};
            }
        }
    }
    if (GAUSS) {
        for (int i = tid; i < QT * 8; i += NT)
            ptbl[i >> 3][i & 7] = PT[(size_t)b * 512 + (qbase + (i >> 3)) * 8 + (i & 7)];
    }
    f32x4 oacc[NSUB];
#pragma unroll
    for (int ns = 0; ns < NSUB; ++ns)
#pragma unroll
        for (int r = 0; r < 4; ++r) oacc[ns][r] = 0.f;
    float m_run[4], l_run[4];
#pragma unroll
    for (int r = 0; r < 4; ++r) { m_run[r] = -1e30f; l_run[r] = 0.f; }

    for (int n0 = 0; n0 < N; n0 += 32) {
        __syncthreads();
        for (int i = tid; i < 2 * 32 * C8; i += NT) {
            int hl = i / (32 * C8);
            int rem = i - hl * 32 * C8;
            int key = rem / C8, c = rem % C8;
            bf16x8 v;
            if (c * 8 < HD) {
                const ushort_t* src = (hl ? Kl : Kh) +
                    (size_t)((b * N) + n0 + key) * 384 + h * HD + c * 8;
                v = *(const bf16x8*)src;
            } else {
                v = bf16x8{};
            }
            *(bf16x8*)&Ksh[hl][key][c * 8] = v;
        }
        for (int i = tid; i < 2 * HD * 4; i += NT) {
            int hl = i / (HD * 4);
            int rem = i - hl * HD * 4;
            int dim = rem >> 2, c = rem & 3;
            const ushort_t* src = (hl ? Vtl : Vth) +
                (size_t)(b * 384 + h * HD + dim) * N + n0 + c * 8;
            *(bf16x8*)&Vsh[hl][dim][c * 8] = *(const bf16x8*)src;
        }
        __syncthreads();

        f32x4 s[2];
#pragma unroll
        for (int sub = 0; sub < 2; ++sub)
#pragma unroll
            for (int r = 0; r < 4; ++r) s[sub][r] = 0.f;
#pragma unroll
        for (int sub = 0; sub < 2; ++sub)
#pragma unroll
            for (int ks = 0; ks < KS; ++ks) {
                bf16x8 kh8 = *(const bf16x8*)&Ksh[0][sub * 16 + l15][ks * 32 + kg * 8];
                bf16x8 kl8 = *(const bf16x8*)&Ksh[1][sub * 16 + l15][ks * 32 + kg * 8];
                s[sub] = MFMA(qf[0][ks], kh8, s[sub], 0, 0, 0);
                s[sub] = MFMA(qf[1][ks], kh8, s[sub], 0, 0, 0);
                s[sub] = MFMA(qf[0][ks], kl8, s[sub], 0, 0, 0);
            }
        if (GAUSS) {
            int widx = n0 >> 7;
#pragma unroll
            for (int sub = 0; sub < 2; ++sub) {
                float wf = (float)((n0 + sub * 16 + l15) & 127);
#pragma unroll
                for (int r = 0; r < 4; ++r) {
                    float ptv = ptbl[w * 16 + kg * 4 + r][widx];
                    float d = wf - ptv;
                    s[sub][r] *= __expf(d * d * (-1.0f / 18.0f));
                }
            }
        }
#pragma unroll
        for (int r = 0; r < 4; ++r) {
            float v = fmaxf(s[0][r], s[1][r]);
            v = fmaxf(v, __shfl_xor(v, 1));
            v = fmaxf(v, __shfl_xor(v, 2));
            v = fmaxf(v, __shfl_xor(v, 4));
            v = fmaxf(v, __shfl_xor(v, 8));
            float mnew = fmaxf(m_run[r], v);
            float alpha = __expf(m_run[r] - mnew);
            m_run[r] = mnew;
            float p0 = __expf(s[0][r] - mnew);
            float p1 = __expf(s[1][r] - mnew);
            float ps = p0 + p1;
            ps += __shfl_xor(ps, 1);
            ps += __shfl_xor(ps, 2);
            ps += __shfl_xor(ps, 4);
            ps += __shfl_xor(ps, 8);
            l_run[r] = l_run[r] * alpha + ps;
#pragma unroll
            for (int ns = 0; ns < NSUB; ++ns) oacc[ns][r] *= alpha;
            unsigned short h0 = f2bf(p0);
            Psh[w][0][kg * 4 + r][l15] = h0;
            Psh[w][1][kg * 4 + r][l15] = f2bf(p0 - bfhi(h0));
            unsigned short h1 = f2bf(p1);
            Psh[w][0][kg * 4 + r][16 + l15] = h1;
            Psh[w][1][kg * 4 + r][16 + l15] = f2bf(p1 - bfhi(h1));
        }
        bf16x8 pfh = *(const bf16x8*)&Psh[w][0][l15][kg * 8];
        bf16x8 pfl = *(const bf16x8*)&Psh[w][1][l15][kg * 8];
#pragma unroll
        for (int ns = 0; ns < NSUB; ++ns) {
            bf16x8 vh8 = *(const bf16x8*)&Vsh[0][ns * 16 + l15][kg * 8];
            bf16x8 vl8 = *(const bf16x8*)&Vsh[1][ns * 16 + l15][kg * 8];
            oacc[ns] = MFMA(pfh, vh8, oacc[ns], 0, 0, 0);
            oacc[ns] = MFMA(pfl, vh8, oacc[ns], 0, 0, 0);
            oacc[ns] = MFMA(pfh, vl8, oacc[ns], 0, 0, 0);
        }
    }
#pragma unroll
    for (int ns = 0; ns < NSUB; ++ns)
#pragma unroll
        for (int r = 0; r < 4; ++r) {
            float val = oacc[ns][r] / l_run[r];
            size_t o = (size_t)(b * QR + qbase + w * 16 + kg * 4 + r) * 384 +
                       h * HD + ns * 16 + l15;
            unsigned short hh = f2bf(val);
            Xh[o] = hh;
            Xl[o] = f2bf(val - bfhi(hh));
        }
}

// ---------------- p_t head ----------------
__global__ __launch_bounds__(256) void pt_kernel(
    const float* __restrict__ T, const float* __restrict__ vpw,
    const float* __restrict__ vpb, float* __restrict__ pt, int rows) {
    int row = blockIdx.x * 4 + (threadIdx.x >> 6);
    int lane = threadIdx.x & 63;
    if (row >= rows) return;
    const float* p = T + (size_t)row * CDIM;
    float s = 0.f;
#pragma unroll
    for (int i = 0; i < CDIM / 64; ++i) s += p[lane + 64 * i] * vpw[lane + 64 * i];
#pragma unroll
    for (int off = 32; off > 0; off >>= 1) s += __shfl_down(s, off);
    if (lane == 0) {
        float x = s + vpb[0];
        pt[row] = 128.f / (1.f + __expf(-x));
    }
}

extern "C" void kernel_launch(void* const* d_in, const int* in_sizes, int n_in,
                              void* d_out, int out_size, void* d_ws, size_t ws_size,
                              hipStream_t stream) {
    const float* q       = (const float*)d_in[0];
    const float* kv      = (const float*)d_in[1];
    const float* Wq      = (const float*)d_in[2];
    const float* Wkv     = (const float*)d_in[3];
    const float* Wproj   = (const float*)d_in[4];
    const float* bproj   = (const float*)d_in[5];
    const float* Wp_w    = (const float*)d_in[6];
    const float* Wp_b    = (const float*)d_in[7];
    const float* vp_w    = (const float*)d_in[8];
    const float* vp_b    = (const float*)d_in[9];
    const float* qpos_w  = (const float*)d_in[10];
    const float* qpos_b  = (const float*)d_in[11];
    const float* ca1_Wq  = (const float*)d_in[12];
    const float* ca1_Wkv = (const float*)d_in[13];
    const float* ca1_Wp  = (const float*)d_in[14];
    const float* ca1_bp  = (const float*)d_in[15];
    const float* ca2_Wq  = (const float*)d_in[16];
    const float* ca2_Wkv = (const float*)d_in[17];
    const float* ca2_Wp  = (const float*)d_in[18];
    const float* ca2_bp  = (const float*)d_in[19];
    const float* lnq1_g  = (const float*)d_in[20];
    const float* lnq1_b  = (const float*)d_in[21];
    const float* lnkv1_g = (const float*)d_in[22];
    const float* lnkv1_b = (const float*)d_in[23];
    const float* lnq2_g  = (const float*)d_in[24];
    const float* lnq2_b  = (const float*)d_in[25];
    const float* lnkv2_g = (const float*)d_in[26];
    const float* lnkv2_b = (const float*)d_in[27];
    float* out = (float*)d_out;

    float* ws = (float*)d_ws;
    float* R0  = ws;                     // 6291456 f
    float* MU  = ws + 6291456;
    float* RS  = MU + 32768;
    float* PTb = RS + 32768;
    ushort_t* U = (ushort_t*)(PTb + 16384);
    ushort_t* SBh = U;  U += 12582912;
    ushort_t* SBl = U;  U += 12582912;
    ushort_t* Qah = U;  U += 6291456;
    ushort_t* Qal = U;  U += 6291456;
    ushort_t* Qmh = U;  U += 786432;
    ushort_t* Qml = U;  U += 786432;
    ushort_t* Kbh = U;  U += 12582912;
    ushort_t* Kbl = U;  U += 12582912;
    ushort_t* Vbh = U;  U += 12582912;
    ushort_t* Vbl = U;  U += 12582912;
    ushort_t* WB  = U;
    const int SQ = 147456, KVW = 294912;
    ushort_t* w_qpos = WB;
    ushort_t* w_c1q  = WB + 294912;
    ushort_t* w_c1kv = WB + 589824;
    ushort_t* w_c1p  = WB + 1179648;
    ushort_t* w_c2q  = WB + 1474560;
    ushort_t* w_c2kv = WB + 1769472;
    ushort_t* w_c2p  = WB + 2359296;
    ushort_t* w_wp   = WB + 2654208;
    ushort_t* w_wq   = WB + 2949120;
    ushort_t* w_wkv  = WB + 3244032;
    ushort_t* w_wpr  = WB + 3833856;

    const float SC_CA = 0.07216878364870323f;   // 192^-0.5
    const float SC_MA = 0.14433756729740643f;   // 48^-0.5
    dim3 blk(256);

    wprep_kernel<<<576, blk, 0, stream>>>(qpos_w, w_qpos, w_qpos + SQ, 384);
    wprep_kernel<<<576, blk, 0, stream>>>(ca1_Wq, w_c1q, w_c1q + SQ, 384);
    wprep_kernel<<<1152, blk, 0, stream>>>(ca1_Wkv, w_c1kv, w_c1kv + KVW, 768);
    wprep_kernel<<<576, blk, 0, stream>>>(ca1_Wp, w_c1p, w_c1p + SQ, 384);
    wprep_kernel<<<576, blk, 0, stream>>>(ca2_Wq, w_c2q, w_c2q + SQ, 384);
    wprep_kernel<<<1152, blk, 0, stream>>>(ca2_Wkv, w_c2kv, w_c2kv + KVW, 768);
    wprep_kernel<<<576, blk, 0, stream>>>(ca2_Wp, w_c2p, w_c2p + SQ, 384);
    wprep_kernel<<<576, blk, 0, stream>>>(Wp_w, w_wp, w_wp + SQ, 384);
    wprep_kernel<<<576, blk, 0, stream>>>(Wq, w_wq, w_wq + SQ, 384);
    wprep_kernel<<<1152, blk, 0, stream>>>(Wkv, w_wkv, w_wkv + KVW, 768);
    wprep_kernel<<<576, blk, 0, stream>>>(Wproj, w_wpr, w_wpr + SQ, 384);

    // 1. P_A(R0) = tile(q,H) @ qpos_w + qpos_b
    split_ln_kernel<<<6144, blk, 0, stream>>>(q, 64, 512, nullptr, nullptr, nullptr, nullptr, SBh, SBl);
    gemm_mfma_kernel<<<dim3(6, 128), blk, 0, stream>>>(SBh, SBl, w_qpos, w_qpos + SQ,
        qpos_b, 384, 0, 1.f, 0, R0, nullptr, nullptr, nullptr, nullptr);
    // 2. CA1
    ln_stats_kernel<<<4096, blk, 0, stream>>>(R0, MU, RS, 16384);
    split_ln_kernel<<<6144, blk, 0, stream>>>(R0, 512, 512, MU, RS, lnq1_g, lnq1_b, SBh, SBl);
    gemm_mfma_kernel<<<dim3(6, 128), blk, 0, stream>>>(SBh, SBl, w_c1q, w_c1q + SQ,
        nullptr, 384, 1, SC_CA, 0, nullptr, Qah, Qal, nullptr, nullptr);
    ln_stats_kernel<<<512, blk, 0, stream>>>(q, MU, RS, 2048);
    split_ln_kernel<<<6144, blk, 0, stream>>>(q, 64, 512, MU, RS, lnkv1_g, lnkv1_b, SBh, SBl);
    gemm_mfma_kernel<<<dim3(12, 128), blk, 0, stream>>>(SBh, SBl, w_c1kv, w_c1kv + KVW,
        nullptr, 768, 2, 1.f, 9, nullptr, Kbh, Kbl, Vbh, Vbl);
    attn_mfma_kernel<192, 192, 8, 0><<<dim3(4, 2, 32), dim3(512), 0, stream>>>(
        Qah, Qal, 512, Kbh, Kbl, Vbh, Vbl, nullptr, SBh, SBl, 512);
    gemm_mfma_kernel<<<dim3(6, 128), blk, 0, stream>>>(SBh, SBl, w_c1p, w_c1p + SQ,
        ca1_bp, 384, 0, 1.f, 0, R0, nullptr, nullptr, nullptr, nullptr);
    // 3. CA2
    ln_stats_kernel<<<4096, blk, 0, stream>>>(R0, MU, RS, 16384);
    split_ln_kernel<<<6144, blk, 0, stream>>>(R0, 512, 512, MU, RS, lnq2_g, lnq2_b, SBh, SBl);
    gemm_mfma_kernel<<<dim3(6, 128), blk, 0, stream>>>(SBh, SBl, w_c2q, w_c2q + SQ,
        nullptr, 384, 1, SC_CA, 0, nullptr, Qah, Qal, nullptr, nullptr);
    ln_stats_kernel<<<8192, blk, 0, stream>>>(kv, MU, RS, 32768);
    split_ln_kernel<<<12288, blk, 0, stream>>>(kv, 1024, 1024, MU, RS, lnkv2_g, lnkv2_b, SBh, SBl);
    gemm_mfma_kernel<<<dim3(12, 256), blk, 0, stream>>>(SBh, SBl, w_c2kv, w_c2kv + KVW,
        nullptr, 768, 2, 1.f, 10, nullptr, Kbh, Kbl, Vbh, Vbl);
    attn_mfma_kernel<192, 192, 8, 0><<<dim3(4, 2, 32), dim3(512), 0, stream>>>(
        Qah, Qal, 512, Kbh, Kbl, Vbh, Vbl, nullptr, SBh, SBl, 1024);
    gemm_mfma_kernel<<<dim3(6, 128), blk, 0, stream>>>(SBh, SBl, w_c2p, w_c2p + SQ,
        ca2_bp, 384, 1, 1.f, 0, nullptr, Qah, Qal, nullptr, nullptr);      // P split
    // 4. T = tanh(P @ Wp_w + Wp_b); PT
    gemm_mfma_kernel<<<dim3(6, 128), blk, 0, stream>>>(Qah, Qal, w_wp, w_wp + SQ,
        Wp_b, 384, 3, 1.f, 0, R0, nullptr, nullptr, nullptr, nullptr);
    pt_kernel<<<4096, blk, 0, stream>>>(R0, vp_w, vp_b, PTb, 16384);
    // 5. main attention
    split_ln_kernel<<<768, blk, 0, stream>>>(q, 64, 64, nullptr, nullptr, nullptr, nullptr, SBh, SBl);
    gemm_mfma_kernel<<<dim3(6, 16), blk, 0, stream>>>(SBh, SBl, w_wq, w_wq + SQ,
        nullptr, 384, 1, SC_MA, 0, nullptr, Qmh, Qml, nullptr, nullptr);
    split_ln_kernel<<<12288, blk, 0, stream>>>(kv, 1024, 1024, nullptr, nullptr, nullptr, nullptr, SBh, SBl);
    gemm_mfma_kernel<<<dim3(12, 256), blk, 0, stream>>>(SBh, SBl, w_wkv, w_wkv + KVW,
        nullptr, 768, 2, 1.f, 10, nullptr, Kbh, Kbl, Vbh, Vbl);
    attn_mfma_kernel<48, 64, 4, 1><<<dim3(1, 8, 32), blk, 0, stream>>>(
        Qmh, Qml, 64, Kbh, Kbl, Vbh, Vbl, PTb, SBh, SBl, 1024);
    // 6. out = X @ Wproj + bproj
    gemm_mfma_kernel<<<dim3(6, 16), blk, 0, stream>>>(SBh, SBl, w_wpr, w_wpr + SQ,
        bproj, 384, 0, 1.f, 0, out, nullptr, nullptr, nullptr, nullptr);
}

// Round 4
// 587.254 us; speedup vs baseline: 4.3739x; 1.7490x over previous
//
#include <hip/hip_runtime.h>
#include <math.h>

#define MFMA __builtin_amdgcn_mfma_f32_16x16x32_bf16
typedef __attribute__((ext_vector_type(8))) short bf16x8;
typedef __attribute__((ext_vector_type(4))) float f32x4;
typedef unsigned short ushort_t;

__device__ __forceinline__ unsigned short f2bf(float x) {
    unsigned u = __float_as_uint(x);
    unsigned r = (u + 0x7FFFu + ((u >> 16) & 1u)) >> 16;
    return (unsigned short)r;
}
__device__ __forceinline__ float bfhi(unsigned short h) {
    return __uint_as_float((unsigned)h << 16);
}

// ---------------- LN stats: one wave per row ----------------
__global__ __launch_bounds__(256) void ln_stats_kernel(
    const float* __restrict__ src, float* __restrict__ mu,
    float* __restrict__ rs, int rows) {
    int row = blockIdx.x * 4 + (threadIdx.x >> 6);
    int lane = threadIdx.x & 63;
    if (row >= rows) return;
    const float* p = src + (size_t)row * 384;
    float s = 0.f, sq = 0.f;
#pragma unroll
    for (int i = 0; i < 6; ++i) {
        float v = p[lane + 64 * i];
        s += v; sq += v * v;
    }
#pragma unroll
    for (int off = 32; off > 0; off >>= 1) {
        s += __shfl_down(s, off);
        sq += __shfl_down(sq, off);
    }
    if (lane == 0) {
        float m = s / 384.f;
        float var = sq / 384.f - m * m;
        mu[row] = m;
        rs[row] = rsqrtf(var + 1e-6f);
    }
}

// ---------------- weight prep: transpose + (g,scale) + hi/lo split ----------------
struct WprepTab {
    const float* src[11]; const float* g[11];
    ushort_t* dh[11]; ushort_t* dl[11];
    float scale[11]; int N[11];
};
__global__ __launch_bounds__(256) void wprep_all(WprepTab t) {
    int e = blockIdx.y;
    int N = t.N[e];
    int idx = blockIdx.x * 256 + threadIdx.x;
    if (idx >= N * 384) return;
    int n = idx / 384, k = idx % 384;
    float x = t.src[e][(size_t)k * N + n] * t.scale[e];
    if (t.g[e]) x *= t.g[e][k];
    unsigned short h = f2bf(x);
    t.dh[e][idx] = h;
    t.dl[e][idx] = f2bf(x - bfhi(h));
}

// ---------------- cm/cb vectors for LN-folded weights ----------------
// cm[c] = -scale * sum_k g_k W[k][c];  cb[c] = scale * sum_k lnb_k W[k][c]
struct CmcbTab {
    const float* src[4]; const float* g[4]; const float* lb[4];
    float* cm[4]; float* cb[4]; float scale[4]; int N[4];
};
__global__ __launch_bounds__(256) void cmcb_all(CmcbTab t) {
    int e = blockIdx.y;
    int N = t.N[e];
    int c = blockIdx.x * 4 + (threadIdx.x >> 6);
    int lane = threadIdx.x & 63;
    if (c >= N) return;
    float s1 = 0.f, s2 = 0.f;
#pragma unroll
    for (int i = 0; i < 6; ++i) {
        int k = lane + 64 * i;
        float w = t.src[e][(size_t)k * N + c];
        s1 += t.g[e][k] * w;
        s2 += t.lb[e][k] * w;
    }
#pragma unroll
    for (int off = 32; off > 0; off >>= 1) {
        s1 += __shfl_down(s1, off);
        s2 += __shfl_down(s2, off);
    }
    if (lane == 0) {
        t.cm[e][c] = -t.scale[e] * s1;
        t.cb[e][c] = t.scale[e] * s2;
    }
}

// ---------------- split-bf16 MFMA GEMM, 384-col slot outputs ----------------
// modes: 0 f32(+bias), 1 tanh->f32, 2 split bf16 [row][384], 3 V^T split
struct Slot {
    const float* bias; const float* cm; const float* cb;
    float* f32o; ushort_t* oh; ushort_t* ol;
    int mode; int kvsh;
};
struct GemmCfg { const float* muA; const float* rsA; Slot s[4]; };

template <int TM, int ASPLIT>
__global__ __launch_bounds__(256) void gemm_k(
    const float* __restrict__ Af,
    const ushort_t* __restrict__ Ah, const ushort_t* __restrict__ Al,
    const ushort_t* __restrict__ Bh, const ushort_t* __restrict__ Bl,
    GemmCfg cfg) {
    constexpr int MI = TM / 64;
    constexpr int AR = TM / 32;
    __shared__ __align__(16) ushort_t Alds[2][TM * 64];
    __shared__ __align__(16) ushort_t Blds[2][64 * 64];
    int m0 = blockIdx.y * TM, n0 = blockIdx.x * 64;
    int tid = threadIdx.x;
    int w = tid >> 6, lane = tid & 63;
    int j = lane & 15, kg = lane >> 4;
    int srow = tid >> 3, sk16 = tid & 7;
    f32x4 acc[MI][4];
#pragma unroll
    for (int mi = 0; mi < MI; ++mi)
#pragma unroll
        for (int ni = 0; ni < 4; ++ni)
#pragma unroll
            for (int r = 0; r < 4; ++r) acc[mi][ni][r] = 0.f;

    for (int ks = 0; ks < 6; ++ks) {
        int kbase = ks * 64 + sk16 * 8;
        __syncthreads();
#pragma unroll
        for (int rnd = 0; rnd < AR; ++rnd) {
            int row = srow + rnd * 32;
            int off = (row << 6) + ((sk16 ^ (row & 7)) << 3);
            if (ASPLIT) {
                size_t ga = (size_t)(m0 + row) * 384 + kbase;
                *(bf16x8*)&Alds[0][off] = *(const bf16x8*)(Ah + ga);
                *(bf16x8*)&Alds[1][off] = *(const bf16x8*)(Al + ga);
            } else {
                const float* ap = Af + (size_t)(m0 + row) * 384 + kbase;
                float4 v0 = *(const float4*)ap;
                float4 v1 = *(const float4*)(ap + 4);
                float vv[8] = {v0.x, v0.y, v0.z, v0.w, v1.x, v1.y, v1.z, v1.w};
                bf16x8 hv, lv;
#pragma unroll
                for (int t = 0; t < 8; ++t) {
                    unsigned short h = f2bf(vv[t]);
                    hv[t] = h;
                    lv[t] = f2bf(vv[t] - bfhi(h));
                }
                *(bf16x8*)&Alds[0][off] = hv;
                *(bf16x8*)&Alds[1][off] = lv;
            }
            if (rnd < 2) {
                size_t gb = (size_t)(n0 + row) * 384 + kbase;
                *(bf16x8*)&Blds[0][off] = *(const bf16x8*)(Bh + gb);
                *(bf16x8*)&Blds[1][off] = *(const bf16x8*)(Bl + gb);
            }
        }
        __syncthreads();
#pragma unroll
        for (int kf = 0; kf < 2; ++kf) {
            bf16x8 afh[MI], afl[MI], bfh[4], bfl[4];
#pragma unroll
            for (int mi = 0; mi < MI; ++mi) {
                int row = w * (TM / 4) + mi * 16 + j;
                int off = (row << 6) + ((((kf << 2) | kg) ^ (row & 7)) << 3);
                afh[mi] = *(const bf16x8*)&Alds[0][off];
                afl[mi] = *(const bf16x8*)&Alds[1][off];
            }
#pragma unroll
            for (int ni = 0; ni < 4; ++ni) {
                int col = ni * 16 + j;
                int off = (col << 6) + ((((kf << 2) | kg) ^ (col & 7)) << 3);
                bfh[ni] = *(const bf16x8*)&Blds[0][off];
                bfl[ni] = *(const bf16x8*)&Blds[1][off];
            }
#pragma unroll
            for (int mi = 0; mi < MI; ++mi)
#pragma unroll
                for (int ni = 0; ni < 4; ++ni) {
                    acc[mi][ni] = MFMA(afh[mi], bfh[ni], acc[mi][ni], 0, 0, 0);
                    acc[mi][ni] = MFMA(afh[mi], bfl[ni], acc[mi][ni], 0, 0, 0);
                    acc[mi][ni] = MFMA(afl[mi], bfh[ni], acc[mi][ni], 0, 0, 0);
                }
        }
    }
    Slot sl = cfg.s[n0 / 384];
    int cb0 = n0 % 384;
#pragma unroll
    for (int mi = 0; mi < MI; ++mi)
#pragma unroll
        for (int ni = 0; ni < 4; ++ni)
#pragma unroll
            for (int r = 0; r < 4; ++r) {
                int row = m0 + w * (TM / 4) + mi * 16 + kg * 4 + r;
                int c2 = cb0 + ni * 16 + j;
                float v = acc[mi][ni][r];
                if (sl.cm) {
                    float rss = cfg.rsA[row];
                    v = rss * v + rss * cfg.muA[row] * sl.cm[c2] + sl.cb[c2];
                }
                if (sl.bias) v += sl.bias[c2];
                if (sl.mode == 0) {
                    sl.f32o[(size_t)row * 384 + c2] = v;
                } else if (sl.mode == 1) {
                    sl.f32o[(size_t)row * 384 + c2] = tanhf(v);
                } else if (sl.mode == 2) {
                    unsigned short h = f2bf(v);
                    sl.oh[(size_t)row * 384 + c2] = h;
                    sl.ol[(size_t)row * 384 + c2] = f2bf(v - bfhi(h));
                } else {
                    int bb = row >> sl.kvsh;
                    int key = row & ((1 << sl.kvsh) - 1);
                    size_t o = (((size_t)bb * 384 + c2) << sl.kvsh) + key;
                    unsigned short h = f2bf(v);
                    sl.oh[o] = h;
                    sl.ol[o] = f2bf(v - bfhi(h));
                }
            }
}

// ---------------- MFMA flash attention, key-chunked, split-bf16 ----------------
// Q split [2048][384] (64 rows/batch, head cols h*HD); K split [(b<<kvsh)+key][384];
// V^T split [(b*384+dim)<<kvsh + key]. FINAL: write split X; else partial O/ML.
template <int HD, int DPAD, int NW, int GAUSS, int FINAL>
__global__ __launch_bounds__(64 * NW) void attn_k(
    const ushort_t* __restrict__ Qh, const ushort_t* __restrict__ Ql,
    const ushort_t* __restrict__ Kh, const ushort_t* __restrict__ Kl,
    const ushort_t* __restrict__ Vth, const ushort_t* __restrict__ Vtl,
    const float* __restrict__ PT,
    ushort_t* __restrict__ Xh, ushort_t* __restrict__ Xl,
    float* __restrict__ Opart, float* __restrict__ ML,
    int kvsh, int nch, int NS, int nh) {
    constexpr int KS = DPAD / 32;
    constexpr int NSUB = HD / 16;
    constexpr int C8 = DPAD / 8;
    constexpr int NT = 64 * NW;
    __shared__ __align__(16) ushort_t Ksh[2][32][DPAD + 8];
    __shared__ __align__(16) ushort_t Vsh[2][HD][40];
    __shared__ __align__(16) ushort_t Psh[NW][2][16][40];
    __shared__ float ptbl[GAUSS ? 64 : 1];
    int b = blockIdx.z, h = blockIdx.y, chunk = blockIdx.x;
    int tid = threadIdx.x;
    int w = tid >> 6, lane = tid & 63;
    int l15 = lane & 15, kg = lane >> 4;

    bf16x8 qf[2][KS];
    {
        size_t qa = (size_t)(b * 64 + w * 16 + l15) * 384 + h * HD + kg * 8;
#pragma unroll
        for (int ks = 0; ks < KS; ++ks) {
            if (ks * 32 + kg * 8 < HD) {
                qf[0][ks] = *(const bf16x8*)(Qh + qa + ks * 32);
                qf[1][ks] = *(const bf16x8*)(Ql + qa + ks * 32);
            } else {
                qf[0][ks] = bf16x8{};
                qf[1][ks] = bf16x8{};
            }
        }
    }
    if (GAUSS) {
        if (tid < 64) ptbl[tid] = PT[b * 64 + tid];
    }
    f32x4 oacc[NSUB];
#pragma unroll
    for (int ns = 0; ns < NSUB; ++ns)
#pragma unroll
        for (int r = 0; r < 4; ++r) oacc[ns][r] = 0.f;
    float m_run[4], l_run[4];
#pragma unroll
    for (int r = 0; r < 4; ++r) { m_run[r] = -1e30f; l_run[r] = 0.f; }

    int kbase0 = chunk * nch;
    for (int t = 0; t < nch; t += 32) {
        int n0 = kbase0 + t;
        __syncthreads();
        for (int i = tid; i < 2 * 32 * C8; i += NT) {
            int hl = i / (32 * C8);
            int rem = i - hl * 32 * C8;
            int key = rem / C8, c = rem % C8;
            bf16x8 v;
            if (c * 8 < HD) {
                const ushort_t* src = (hl ? Kl : Kh) +
                    ((size_t)((b << kvsh) + n0 + key)) * 384 + h * HD + c * 8;
                v = *(const bf16x8*)src;
            } else {
                v = bf16x8{};
            }
            *(bf16x8*)&Ksh[hl][key][c * 8] = v;
        }
        for (int i = tid; i < 2 * HD * 4; i += NT) {
            int hl = i / (HD * 4);
            int rem = i - hl * HD * 4;
            int dim = rem >> 2, c = rem & 3;
            const ushort_t* src = (hl ? Vtl : Vth) +
                (((size_t)(b * 384 + h * HD + dim)) << kvsh) + n0 + c * 8;
            *(bf16x8*)&Vsh[hl][dim][c * 8] = *(const bf16x8*)src;
        }
        __syncthreads();

        f32x4 shh[2], slh[2], shl[2];
#pragma unroll
        for (int sub = 0; sub < 2; ++sub)
#pragma unroll
            for (int r = 0; r < 4; ++r) { shh[sub][r] = 0.f; slh[sub][r] = 0.f; shl[sub][r] = 0.f; }
#pragma unroll
        for (int sub = 0; sub < 2; ++sub)
#pragma unroll
            for (int ks = 0; ks < KS; ++ks) {
                bf16x8 kh8 = *(const bf16x8*)&Ksh[0][sub * 16 + l15][ks * 32 + kg * 8];
                bf16x8 kl8 = *(const bf16x8*)&Ksh[1][sub * 16 + l15][ks * 32 + kg * 8];
                shh[sub] = MFMA(qf[0][ks], kh8, shh[sub], 0, 0, 0);
                slh[sub] = MFMA(qf[1][ks], kh8, slh[sub], 0, 0, 0);
                shl[sub] = MFMA(qf[0][ks], kl8, shl[sub], 0, 0, 0);
            }
        f32x4 s[2];
#pragma unroll
        for (int sub = 0; sub < 2; ++sub)
#pragma unroll
            for (int r = 0; r < 4; ++r)
                s[sub][r] = shh[sub][r] + slh[sub][r] + shl[sub][r];
        if (GAUSS) {
            int win = n0 >> 7;
#pragma unroll
            for (int sub = 0; sub < 2; ++sub) {
                float wpos = (float)((n0 + sub * 16 + l15) & 127);
#pragma unroll
                for (int r = 0; r < 4; ++r) {
                    float ptv = ptbl[((w * 16 + kg * 4 + r) * 8 + win) & 63];
                    float d = wpos - ptv;
                    s[sub][r] *= __expf(d * d * (-1.0f / 18.0f));
                }
            }
        }
#pragma unroll
        for (int r = 0; r < 4; ++r) {
            float v = fmaxf(s[0][r], s[1][r]);
            v = fmaxf(v, __shfl_xor(v, 1));
            v = fmaxf(v, __shfl_xor(v, 2));
            v = fmaxf(v, __shfl_xor(v, 4));
            v = fmaxf(v, __shfl_xor(v, 8));
            float mnew = fmaxf(m_run[r], v);
            float alpha = __expf(m_run[r] - mnew);
            m_run[r] = mnew;
            float p0 = __expf(s[0][r] - mnew);
            float p1 = __expf(s[1][r] - mnew);
            float ps = p0 + p1;
            ps += __shfl_xor(ps, 1);
            ps += __shfl_xor(ps, 2);
            ps += __shfl_xor(ps, 4);
            ps += __shfl_xor(ps, 8);
            l_run[r] = l_run[r] * alpha + ps;
#pragma unroll
            for (int ns = 0; ns < NSUB; ++ns) oacc[ns][r] *= alpha;
            unsigned short h0 = f2bf(p0);
            Psh[w][0][kg * 4 + r][l15] = h0;
            Psh[w][1][kg * 4 + r][l15] = f2bf(p0 - bfhi(h0));
            unsigned short h1 = f2bf(p1);
            Psh[w][0][kg * 4 + r][16 + l15] = h1;
            Psh[w][1][kg * 4 + r][16 + l15] = f2bf(p1 - bfhi(h1));
        }
        bf16x8 pfh = *(const bf16x8*)&Psh[w][0][l15][kg * 8];
        bf16x8 pfl = *(const bf16x8*)&Psh[w][1][l15][kg * 8];
#pragma unroll
        for (int ns = 0; ns < NSUB; ++ns) {
            bf16x8 vh8 = *(const bf16x8*)&Vsh[0][ns * 16 + l15][kg * 8];
            bf16x8 vl8 = *(const bf16x8*)&Vsh[1][ns * 16 + l15][kg * 8];
            oacc[ns] = MFMA(pfh, vh8, oacc[ns], 0, 0, 0);
            oacc[ns] = MFMA(pfl, vh8, oacc[ns], 0, 0, 0);
            oacc[ns] = MFMA(pfh, vl8, oacc[ns], 0, 0, 0);
        }
    }
    if (FINAL) {
#pragma unroll
        for (int ns = 0; ns < NSUB; ++ns)
#pragma unroll
            for (int r = 0; r < 4; ++r) {
                float val = oacc[ns][r] / l_run[r];
                size_t o = (size_t)(b * 64 + w * 16 + kg * 4 + r) * 384 +
                           h * HD + ns * 16 + l15;
                unsigned short hh = f2bf(val);
                Xh[o] = hh;
                Xl[o] = f2bf(val - bfhi(hh));
            }
    } else {
#pragma unroll
        for (int r = 0; r < 4; ++r) {
            int rq = w * 16 + kg * 4 + r;
            size_t Pidx = ((size_t)((b * nh + h) * 64 + rq)) * NS + chunk;
#pragma unroll
            for (int ns = 0; ns < NSUB; ++ns)
                Opart[Pidx * HD + ns * 16 + l15] = oacc[ns][r];
            if (l15 == 0) {
                ML[Pidx * 2] = m_run[r];
                ML[Pidx * 2 + 1] = l_run[r];
            }
        }
    }
}

// ---------------- flash combine: merge NS chunk partials ----------------
template <int HD>
__global__ __launch_bounds__(256) void comb_k(
    const float* __restrict__ Opart, const float* __restrict__ ML,
    ushort_t* __restrict__ Xh, ushort_t* __restrict__ Xl,
    int NS, int nh) {
    int gw = blockIdx.x * 4 + (threadIdx.x >> 6);
    int lane = threadIdx.x & 63;
    if (gw >= 2048 * nh) return;
    int r_ = gw / nh, h = gw % nh;
    int b = r_ >> 6, rq = r_ & 63;
    size_t Pb = ((size_t)((b * nh + h) * 64 + rq)) * NS;
    float M = -1e30f;
    for (int c = 0; c < NS; ++c) M = fmaxf(M, ML[(Pb + c) * 2]);
    float wgt[8];
    float L = 0.f;
    for (int c = 0; c < NS; ++c) {
        wgt[c] = __expf(ML[(Pb + c) * 2] - M);
        L += wgt[c] * ML[(Pb + c) * 2 + 1];
    }
    float invL = 1.f / L;
    for (int d = lane; d < HD; d += 64) {
        float o = 0.f;
        for (int c = 0; c < NS; ++c) o += wgt[c] * Opart[(Pb + c) * HD + d];
        o *= invL;
        size_t xo = (size_t)r_ * 384 + h * HD + d;
        unsigned short hh = f2bf(o);
        Xh[xo] = hh;
        Xl[xo] = f2bf(o - bfhi(hh));
    }
}

// ---------------- p_t head ----------------
__global__ __launch_bounds__(256) void pt_kernel(
    const float* __restrict__ T, const float* __restrict__ vpw,
    const float* __restrict__ vpb, float* __restrict__ pt, int rows) {
    int row = blockIdx.x * 4 + (threadIdx.x >> 6);
    int lane = threadIdx.x & 63;
    if (row >= rows) return;
    const float* p = T + (size_t)row * 384;
    float s = 0.f;
#pragma unroll
    for (int i = 0; i < 6; ++i) s += p[lane + 64 * i] * vpw[lane + 64 * i];
#pragma unroll
    for (int off = 32; off > 0; off >>= 1) s += __shfl_down(s, off);
    if (lane == 0) {
        float x = s + vpb[0];
        pt[row] = 128.f / (1.f + __expf(-x));
    }
}

extern "C" void kernel_launch(void* const* d_in, const int* in_sizes, int n_in,
                              void* d_out, int out_size, void* d_ws, size_t ws_size,
                              hipStream_t stream) {
    const float* q       = (const float*)d_in[0];
    const float* kv      = (const float*)d_in[1];
    const float* Wq      = (const float*)d_in[2];
    const float* Wkv     = (const float*)d_in[3];
    const float* Wproj   = (const float*)d_in[4];
    const float* bproj   = (const float*)d_in[5];
    const float* Wp_w    = (const float*)d_in[6];
    const float* Wp_b    = (const float*)d_in[7];
    const float* vp_w    = (const float*)d_in[8];
    const float* vp_b    = (const float*)d_in[9];
    const float* qpos_w  = (const float*)d_in[10];
    const float* qpos_b  = (const float*)d_in[11];
    const float* ca1_Wq  = (const float*)d_in[12];
    const float* ca1_Wkv = (const float*)d_in[13];
    const float* ca1_Wp  = (const float*)d_in[14];
    const float* ca1_bp  = (const float*)d_in[15];
    const float* ca2_Wq  = (const float*)d_in[16];
    const float* ca2_Wkv = (const float*)d_in[17];
    const float* ca2_Wp  = (const float*)d_in[18];
    const float* ca2_bp  = (const float*)d_in[19];
    const float* lnq1_g  = (const float*)d_in[20];
    const float* lnq1_b  = (const float*)d_in[21];
    const float* lnkv1_g = (const float*)d_in[22];
    const float* lnkv1_b = (const float*)d_in[23];
    const float* lnq2_g  = (const float*)d_in[24];
    const float* lnq2_b  = (const float*)d_in[25];
    const float* lnkv2_g = (const float*)d_in[26];
    const float* lnkv2_b = (const float*)d_in[27];
    float* out = (float*)d_out;

    const float SC_CA = 0.07216878364870323f;   // 192^-0.5
    const float SC_MA = 0.14433756729740643f;   // 48^-0.5

    float* F = (float*)d_ws;
    float* R0 = F;    F += 786432;
    float* R1 = F;    F += 786432;
    float* MUq = F;   F += 2048;
    float* RSq = F;   F += 2048;
    float* MUkv = F;  F += 32768;
    float* RSkv = F;  F += 32768;
    float* MUpa = F;  F += 2048;
    float* RSpa = F;  F += 2048;
    float* MUpb = F;  F += 2048;
    float* RSpb = F;  F += 2048;
    float* PTb = F;   F += 2048;
    float* CM = F;    F += 2304;
    float* CB = F;    F += 2304;
    float* OP = F;    F += 6291456;
    float* MLb = F;   F += 262144;
    ushort_t* U = (ushort_t*)F;
    ushort_t* WB1h = U; U += 589824;
    ushort_t* WB1l = U; U += 589824;
    ushort_t* WB5h = U; U += 589824;
    ushort_t* WB5l = U; U += 589824;
    ushort_t* W2h = U;  U += 147456;
    ushort_t* W2l = U;  U += 147456;
    ushort_t* W3h = U;  U += 147456;
    ushort_t* W3l = U;  U += 147456;
    ushort_t* W4h = U;  U += 147456;
    ushort_t* W4l = U;  U += 147456;
    ushort_t* W6h = U;  U += 147456;
    ushort_t* W6l = U;  U += 147456;
    ushort_t* W7h = U;  U += 147456;
    ushort_t* W7l = U;  U += 147456;
    ushort_t* W10h = U; U += 147456;
    ushort_t* W10l = U; U += 147456;
    ushort_t* Qch = U;  U += 786432;
    ushort_t* Qcl = U;  U += 786432;
    ushort_t* Qmh = U;  U += 786432;
    ushort_t* Qml = U;  U += 786432;
    ushort_t* Xh = U;   U += 786432;
    ushort_t* Xl = U;   U += 786432;
    ushort_t* Ph = U;   U += 786432;
    ushort_t* Pl = U;   U += 786432;
    ushort_t* K1h = U;  U += 786432;
    ushort_t* K1l = U;  U += 786432;
    ushort_t* V1h = U;  U += 786432;
    ushort_t* V1l = U;  U += 786432;
    ushort_t* K2h = U;  U += 12582912;
    ushort_t* K2l = U;  U += 12582912;
    ushort_t* V2h = U;  U += 12582912;
    ushort_t* V2l = U;  U += 12582912;
    ushort_t* Kmh = U;  U += 12582912;
    ushort_t* Kml = U;  U += 12582912;
    ushort_t* Vmh = U;  U += 12582912;
    ushort_t* Vml = U;  U += 12582912;

    dim3 blk(256);

    // stats on raw inputs
    ln_stats_kernel<<<512, blk, 0, stream>>>(q, MUq, RSq, 2048);
    ln_stats_kernel<<<8192, blk, 0, stream>>>(kv, MUkv, RSkv, 32768);

    // weight prep
    WprepTab wt{};
    const float* wsrc[11] = {qpos_w, ca1_Wkv, Wq, ca2_Wkv, Wkv, ca1_Wq,
                             ca1_Wp, ca2_Wq, ca2_Wp, Wp_w, Wproj};
    const float* wg[11] = {nullptr, lnkv1_g, nullptr, lnkv2_g, nullptr, lnq1_g,
                           nullptr, lnq2_g, nullptr, nullptr, nullptr};
    ushort_t* wdh[11] = {WB1h, WB1h + 384 * 384, WB1h + 1152 * 384,
                         WB5h, WB5h + 768 * 384, W2h, W3h, W4h, W6h, W7h, W10h};
    ushort_t* wdl[11] = {WB1l, WB1l + 384 * 384, WB1l + 1152 * 384,
                         WB5l, WB5l + 768 * 384, W2l, W3l, W4l, W6l, W7l, W10l};
    float wsc[11] = {1.f, 1.f, SC_MA, 1.f, 1.f, SC_CA, 1.f, SC_CA, 1.f, 1.f, 1.f};
    int wn[11] = {384, 768, 384, 768, 768, 384, 384, 384, 384, 384, 384};
    for (int i = 0; i < 11; ++i) {
        wt.src[i] = wsrc[i]; wt.g[i] = wg[i]; wt.dh[i] = wdh[i];
        wt.dl[i] = wdl[i]; wt.scale[i] = wsc[i]; wt.N[i] = wn[i];
    }
    wprep_all<<<dim3(1152, 11), blk, 0, stream>>>(wt);

    CmcbTab ct{};
    const float* csrc[4] = {ca1_Wq, ca1_Wkv, ca2_Wq, ca2_Wkv};
    const float* cg[4] = {lnq1_g, lnkv1_g, lnq2_g, lnkv2_g};
    const float* cl[4] = {lnq1_b, lnkv1_b, lnq2_b, lnkv2_b};
    float* ccm[4] = {CM, CM + 384, CM + 1152, CM + 1536};
    float* ccb[4] = {CB, CB + 384, CB + 1152, CB + 1536};
    float csc[4] = {SC_CA, 1.f, SC_CA, 1.f};
    int cn[4] = {384, 768, 384, 768};
    for (int i = 0; i < 4; ++i) {
        ct.src[i] = csrc[i]; ct.g[i] = cg[i]; ct.lb[i] = cl[i];
        ct.cm[i] = ccm[i]; ct.cb[i] = ccb[i]; ct.scale[i] = csc[i]; ct.N[i] = cn[i];
    }
    cmcb_all<<<dim3(192, 4), blk, 0, stream>>>(ct);

    // G1: A=q [2048], W = [qpos | ca1_KV (LN q) | Wq*sc]
    GemmCfg g1{};
    g1.muA = MUq; g1.rsA = RSq;
    g1.s[0] = {qpos_b, nullptr, nullptr, R0, nullptr, nullptr, 0, 0};
    g1.s[1] = {nullptr, CM + 384, CB + 384, nullptr, K1h, K1l, 2, 0};
    g1.s[2] = {nullptr, CM + 768, CB + 768, nullptr, V1h, V1l, 3, 6};
    g1.s[3] = {nullptr, nullptr, nullptr, nullptr, Qmh, Qml, 2, 0};
    gemm_k<64, 0><<<dim3(24, 32), blk, 0, stream>>>(q, nullptr, nullptr, WB1h, WB1l, g1);

    ln_stats_kernel<<<512, blk, 0, stream>>>(R0, MUpa, RSpa, 2048);

    // G2: CAQ1 = LN(P_A) @ ca1_Wq * sc  (LN folded)
    GemmCfg g2{};
    g2.muA = MUpa; g2.rsA = RSpa;
    g2.s[0] = {nullptr, CM, CB, nullptr, Qch, Qcl, 2, 0};
    gemm_k<64, 0><<<dim3(6, 32), blk, 0, stream>>>(R0, nullptr, nullptr, W2h, W2l, g2);

    // CA1 attention (64 keys, final)
    attn_k<192, 192, 4, 0, 1><<<dim3(1, 2, 32), blk, 0, stream>>>(
        Qch, Qcl, K1h, K1l, V1h, V1l, nullptr, Xh, Xl, nullptr, nullptr, 6, 64, 1, 2);

    // G3: P_B = X @ ca1_Wp + bp
    GemmCfg g3{};
    g3.s[0] = {ca1_bp, nullptr, nullptr, R1, nullptr, nullptr, 0, 0};
    gemm_k<64, 1><<<dim3(6, 32), blk, 0, stream>>>(nullptr, Xh, Xl, W3h, W3l, g3);

    ln_stats_kernel<<<512, blk, 0, stream>>>(R1, MUpb, RSpb, 2048);

    // G4: CAQ2 = LN(P_B) @ ca2_Wq * sc
    GemmCfg g4{};
    g4.muA = MUpb; g4.rsA = RSpb;
    g4.s[0] = {nullptr, CM + 1152, CB + 1152, nullptr, Qch, Qcl, 2, 0};
    gemm_k<64, 0><<<dim3(6, 32), blk, 0, stream>>>(R1, nullptr, nullptr, W4h, W4l, g4);

    // G5: A=kv [32768], W = [ca2_KV (LN kv) | main KV]
    GemmCfg g5{};
    g5.muA = MUkv; g5.rsA = RSkv;
    g5.s[0] = {nullptr, CM + 1536, CB + 1536, nullptr, K2h, K2l, 2, 0};
    g5.s[1] = {nullptr, CM + 1920, CB + 1920, nullptr, V2h, V2l, 3, 10};
    g5.s[2] = {nullptr, nullptr, nullptr, nullptr, Kmh, Kml, 2, 0};
    g5.s[3] = {nullptr, nullptr, nullptr, nullptr, Vmh, Vml, 3, 10};
    gemm_k<128, 0><<<dim3(24, 256), blk, 0, stream>>>(kv, nullptr, nullptr, WB5h, WB5l, g5);

    // CA2 attention (1024 keys, 8 chunks) + combine
    attn_k<192, 192, 4, 0, 0><<<dim3(8, 2, 32), blk, 0, stream>>>(
        Qch, Qcl, K2h, K2l, V2h, V2l, nullptr, nullptr, nullptr, OP, MLb, 10, 128, 8, 2);
    comb_k<192><<<1024, blk, 0, stream>>>(OP, MLb, Xh, Xl, 8, 2);

    // G6: P = X @ ca2_Wp + bp (split)
    GemmCfg g6{};
    g6.s[0] = {ca2_bp, nullptr, nullptr, nullptr, Ph, Pl, 2, 0};
    gemm_k<64, 1><<<dim3(6, 32), blk, 0, stream>>>(nullptr, Xh, Xl, W6h, W6l, g6);

    // G7: T = tanh(P @ Wp_w + Wp_b)
    GemmCfg g7{};
    g7.s[0] = {Wp_b, nullptr, nullptr, R0, nullptr, nullptr, 1, 0};
    gemm_k<64, 1><<<dim3(6, 32), blk, 0, stream>>>(nullptr, Ph, Pl, W7h, W7l, g7);

    pt_kernel<<<512, blk, 0, stream>>>(R0, vp_w, vp_b, PTb, 2048);

    // main attention (gauss, 8 chunks) + combine
    attn_k<48, 64, 4, 1, 0><<<dim3(8, 8, 32), blk, 0, stream>>>(
        Qmh, Qml, Kmh, Kml, Vmh, Vml, PTb, nullptr, nullptr, OP, MLb, 10, 128, 8, 8);
    comb_k<48><<<4096, blk, 0, stream>>>(OP, MLb, Xh, Xl, 8, 8);

    // G10: out = X @ Wproj + bproj
    GemmCfg g10{};
    g10.s[0] = {bproj, nullptr, nullptr, out, nullptr, nullptr, 0, 0};
    gemm_k<64, 1><<<dim3(6, 32), blk, 0, stream>>>(nullptr, Xh, Xl, W10h, W10l, g10);
}